// Round 1
// 28853.366 us; speedup vs baseline: 1.0419x; 1.0419x over previous
//
#include <hip/hip_runtime.h>

using short8 = __attribute__((ext_vector_type(8))) short;
using f32x4  = __attribute__((ext_vector_type(4))) float;

#define NN 4096
#define TT 365
#define DD 16
#define HH 256
#define PP 2
#define TD (TT*DD)      // 5840
#define TP (TT*PP)      // 730
#define KG 320          // gates K: [h(256) | x(16) | pad(48)]  (was 384)
#define ASCALE 4096.0f
#define AINV   (1.0f/4096.0f)

__device__ __forceinline__ unsigned short f2bf(float f) {
    union { float f; unsigned u; } v; v.f = f;
    unsigned r = v.u + 0x7FFFu + ((v.u >> 16) & 1u);   // RNE
    return (unsigned short)(r >> 16);
}
// float -> OCP e4m3fn, RNE, saturating at 448
__device__ __forceinline__ unsigned char f2e4m3(float f) {
    union { float f; unsigned u; } v; v.f = f;
    unsigned s = (v.u >> 24) & 0x80u;
    unsigned au = v.u & 0x7fffffffu;
    if (au >= 0x43E00000u) return (unsigned char)(s | 0x7E);   // >=448 -> 448
    if (au < 0x3C800000u) {                                    // <2^-6: subnormal
        int m = __float2int_rn(__uint_as_float(au) * 512.0f);  // 0..8
        return (unsigned char)(s | (unsigned)m);
    }
    unsigned r = au + 0x7FFFFu + ((au >> 20) & 1u);            // RNE to 3 mantissa bits
    return (unsigned char)(s | ((r >> 20) - 0x3C0u));
}
__device__ __forceinline__ float sigmoidf_(float x) {
    return 1.0f / (1.0f + __expf(-x));
}
__device__ __forceinline__ float tanhf_(float x) {
    float t = __expf(2.0f * x);
    return (t - 1.0f) / (t + 1.0f);
}
__device__ __forceinline__ void async16(const void* g, void* l) {
    __builtin_amdgcn_global_load_lds(
        (const __attribute__((address_space(1))) void*)g,
        (__attribute__((address_space(3))) void*)l, 16, 0, 0);
}

// ---------------------------------------------------------------------------
// bf16 core, DOUBLE-BUFFERED prefetch: 256 thr = 4 waves 2x2. BN=128, BK=64,
// BM=32*TI. C = Amat(row-major,lda) @ Bt^T (Bt[col][k],ldb). 16B-block XOR
// swizzle (source-side pre-swizzle + swizzled read).
// C frag: col = lane&15, row = (lane>>4)*4 + reg.
// As: 2 * TI*32*64 shorts.  Bs: 2 * 128*64 shorts.
// ---------------------------------------------------------------------------
template<int TI>
__device__ __forceinline__ void gemm_core_db(
    const unsigned short* __restrict__ Amat, int lda,
    const unsigned short* __restrict__ Bt,  int ldb,
    int k_len, int row0, int col0,
    unsigned short* As, unsigned short* Bs,
    f32x4 (&acc)[TI][4])
{
    const int tid  = threadIdx.x;
    const int lane = tid & 63;
    const int wave = tid >> 6;
    const int srow = lane >> 3;
    const int sblk = lane & 7;
    const int ABUF = TI * 32 * 64;     // shorts per A buffer
    const int BBUF = 128 * 64;         // shorts per B buffer

    const unsigned short* Ag = Amat + (size_t)(row0 + wave*8 + srow) * lda
                                    + ((sblk ^ srow) * 8);
    const unsigned short* Bg = Bt   + (size_t)(col0 + wave*8 + srow) * ldb
                                    + ((sblk ^ srow) * 8);

    const int fr = lane & 15;
    const int fq = lane >> 4;
    const int wr = (wave >> 1) * (TI * 16);
    const int wc = (wave & 1) * 64;
    const int off0 = ((fq ^ (fr & 7)) * 8);

    // prologue: stage tile 0 into buffer 0
    {
        unsigned short* AsW = As + wave * 512;
        unsigned short* BsW = Bs + wave * 512;
        #pragma unroll
        for (int q = 0; q < TI; q++) async16(Ag + (size_t)q * 32 * lda, AsW + q * 2048);
        #pragma unroll
        for (int q = 0; q < 4;  q++) async16(Bg + (size_t)q * 32 * ldb, BsW + q * 2048);
    }
    asm volatile("s_waitcnt vmcnt(0)" ::: "memory");
    __syncthreads();

    const int nk = k_len >> 6;
    int sel = 0;
    for (int it = 0; it < nk; ++it) {
        if (it + 1 < nk) {   // prefetch next tile into other buffer
            const unsigned short* Agn = Ag + (it + 1) * 64;
            const unsigned short* Bgn = Bg + (it + 1) * 64;
            unsigned short* AsW = As + (sel ^ 1) * ABUF + wave * 512;
            unsigned short* BsW = Bs + (sel ^ 1) * BBUF + wave * 512;
            #pragma unroll
            for (int q = 0; q < TI; q++) async16(Agn + (size_t)q * 32 * lda, AsW + q * 2048);
            #pragma unroll
            for (int q = 0; q < 4;  q++) async16(Bgn + (size_t)q * 32 * ldb, BsW + q * 2048);
        }
        const unsigned short* Ab = As + sel * ABUF;
        const unsigned short* Bb = Bs + sel * BBUF;
        #pragma unroll
        for (int kh = 0; kh < 2; kh++) {
            const int off = off0 ^ (kh * 32);
            short8 a[TI], b[4];
            #pragma unroll
            for (int i = 0; i < TI; i++)
                a[i] = *(const short8*)(Ab + (wr + i*16 + fr) * 64 + off);
            #pragma unroll
            for (int j = 0; j < 4;  j++)
                b[j] = *(const short8*)(Bb + (wc + j*16 + fr) * 64 + off);
            #pragma unroll
            for (int i = 0; i < TI; i++)
                #pragma unroll
                for (int j = 0; j < 4; j++)
                    acc[i][j] = __builtin_amdgcn_mfma_f32_16x16x32_bf16(
                        a[i], b[j], acc[i][j], 0, 0, 0);
        }
        asm volatile("s_waitcnt vmcnt(0)" ::: "memory");  // prefetch landed
        __syncthreads();                                   // all reads of sel done
        sel ^= 1;
    }
}

// ---------------------------------------------------------------------------
// fp8 core, DOUBLE-BUFFERED, 128x128 tile (TI=4): C = A8 @ B8^T, both
// row-major [*][NN] bytes, BK=128. As/Bs: 2 * 128*128 bytes each.
// ---------------------------------------------------------------------------
__device__ __forceinline__ void gemm8_db(
    const unsigned char* __restrict__ Amat,
    const unsigned char* __restrict__ Bmat,
    int kb, int klen, int row0, int col0,
    unsigned char* As, unsigned char* Bs,
    f32x4 (&acc)[4][4])
{
    const int tid  = threadIdx.x;
    const int lane = tid & 63;
    const int wave = tid >> 6;
    const int srow = lane >> 3;
    const int sblk = lane & 7;
    const int BUF = 128 * 128;

    const unsigned char* Ag = Amat + (size_t)(row0 + wave*8 + srow) * NN
                                   + ((sblk ^ srow) * 16) + kb;
    const unsigned char* Bg = Bmat + (size_t)(col0 + wave*8 + srow) * NN
                                   + ((sblk ^ srow) * 16) + kb;

    const int fr = lane & 15;
    const int fq = lane >> 4;
    const int wr = (wave >> 1) * 64;
    const int wc = (wave & 1) * 64;
    int offk[4];
    #pragma unroll
    for (int kq = 0; kq < 4; kq++)
        offk[kq] = (((kq*2 + (fq >> 1)) ^ (fr & 7)) << 4) + ((fq & 1) << 3);

    {
        unsigned char* AsW = As + wave * 1024;
        unsigned char* BsW = Bs + wave * 1024;
        #pragma unroll
        for (int q = 0; q < 4; q++) async16(Ag + (size_t)q * 32 * NN, AsW + q * 4096);
        #pragma unroll
        for (int q = 0; q < 4; q++) async16(Bg + (size_t)q * 32 * NN, BsW + q * 4096);
    }
    asm volatile("s_waitcnt vmcnt(0)" ::: "memory");
    __syncthreads();

    const int nk = klen >> 7;
    int sel = 0;
    for (int it = 0; it < nk; ++it) {
        if (it + 1 < nk) {
            const unsigned char* Agn = Ag + (size_t)(it + 1) * 128;
            const unsigned char* Bgn = Bg + (size_t)(it + 1) * 128;
            unsigned char* AsW = As + (sel ^ 1) * BUF + wave * 1024;
            unsigned char* BsW = Bs + (sel ^ 1) * BUF + wave * 1024;
            #pragma unroll
            for (int q = 0; q < 4; q++) async16(Agn + (size_t)q * 32 * NN, AsW + q * 4096);
            #pragma unroll
            for (int q = 0; q < 4; q++) async16(Bgn + (size_t)q * 32 * NN, BsW + q * 4096);
        }
        const unsigned char* Ab = As + sel * BUF;
        const unsigned char* Bb = Bs + sel * BUF;
        #pragma unroll
        for (int kq = 0; kq < 4; kq++) {
            long a[4], b[4];
            #pragma unroll
            for (int i = 0; i < 4; i++) a[i] = *(const long*)(Ab + (wr + i*16 + fr) * 128 + offk[kq]);
            #pragma unroll
            for (int j = 0; j < 4; j++) b[j] = *(const long*)(Bb + (wc + j*16 + fr) * 128 + offk[kq]);
            #pragma unroll
            for (int i = 0; i < 4; i++)
                #pragma unroll
                for (int j = 0; j < 4; j++)
                    acc[i][j] = __builtin_amdgcn_mfma_f32_16x16x32_fp8_fp8(
                        a[i], b[j], acc[i][j], 0, 0, 0);
        }
        asm volatile("s_waitcnt vmcnt(0)" ::: "memory");
        __syncthreads();
        sel ^= 1;
    }
}

// ---------------- prep (once per launch) ----------------

__global__ __launch_bounds__(256) void k_prep_a(const float* __restrict__ A,
                                                unsigned char* __restrict__ A8) {
    size_t i = (size_t)blockIdx.x * blockDim.x + threadIdx.x;
    size_t stride = (size_t)gridDim.x * blockDim.x;
    size_t total = (size_t)NN * NN / 4;
    for (; i < total; i += stride) {
        float4 v = ((const float4*)A)[i];
        unsigned pk = (unsigned)f2e4m3(v.x * ASCALE)
                    | ((unsigned)f2e4m3(v.y * ASCALE) << 8)
                    | ((unsigned)f2e4m3(v.z * ASCALE) << 16)
                    | ((unsigned)f2e4m3(v.w * ASCALE) << 24);
        ((unsigned*)A8)[i] = pk;
    }
}

// WzTb[col][k] col 0..1023 gate-interleaved (c2=4h+g, oc=g*256+h):
//   k<256 -> rkernel[k][oc]; 256<=k<272 -> kernel[k-256][oc]; else 0
// WgT[col][k] col 0..511, k 0..255: col<256 -> Wgh[k][col] else Wgc[k][col-256]
// W2T[col][k] col 0..511, k 0..1023 over LHS3=[h_cur|h_graph|c_cur|c_graph]
__global__ __launch_bounds__(256) void k_prep_w(
    const float* __restrict__ Wgh, const float* __restrict__ Wgc,
    const float* __restrict__ rk,  const float* __restrict__ kern,
    const float* __restrict__ lb,
    const float* __restrict__ Whc, const float* __restrict__ Whp,
    const float* __restrict__ Wcc, const float* __restrict__ Wcp,
    unsigned short* __restrict__ WzTb, unsigned short* __restrict__ WgT,
    unsigned short* __restrict__ W2T, float* __restrict__ biasg)
{
    int i = blockIdx.x * blockDim.x + threadIdx.x;
    int stride = gridDim.x * blockDim.x;
    for (int x = i; x < 1024 * KG; x += stride) {
        int col = x / KG, k = x % KG;
        int oc = (col & 3) * 256 + (col >> 2);
        float val = 0.f;
        if (k < 256) val = rk[k * 1024 + oc];
        else if (k < 272) val = kern[(k - 256) * 1024 + oc];
        WzTb[x] = f2bf(val);
    }
    for (int x = i; x < 512 * 256; x += stride) {
        int col = x >> 8, k = x & 255;
        float val = (col < 256) ? Wgh[k * 256 + col] : Wgc[k * 256 + (col - 256)];
        WgT[x] = f2bf(val);
    }
    for (int x = i; x < 512 * 1024; x += stride) {
        int col = x >> 10, k = x & 1023;
        float val = 0.f;
        if (col < 256) {
            if (k < 256)      val = Whc[k * 256 + col];
            else if (k < 512) val = Whp[(k - 256) * 256 + col];
        } else {
            int c2 = col - 256;
            if (k >= 512 && k < 768) val = Wcc[(k - 512) * 256 + c2];
            else if (k >= 768)       val = Wcp[(k - 768) * 256 + c2];
        }
        W2T[x] = f2bf(val);
    }
    for (int x = i; x < 1024; x += stride)
        biasg[x] = lb[(x & 3) * 256 + (x >> 2)];
}

// HCb[n][KG]: 0..255 h_prev bf16, 256..271 x_t, rest 0. hcT8, Cstate zeroed.
__global__ __launch_bounds__(256) void k_prep_s(const float* __restrict__ inputs,
                                                unsigned short* __restrict__ HCb,
                                                unsigned char* __restrict__ hcT8,
                                                float* __restrict__ Cstate)
{
    int i = blockIdx.x * blockDim.x + threadIdx.x;
    int stride = gridDim.x * blockDim.x;
    for (int x = i; x < NN * KG; x += stride) {
        int n = x / KG, col = x % KG;
        unsigned short v = 0;
        if (col >= 256 && col < 272)
            v = f2bf(inputs[(size_t)n * TD + (col - 256)]);
        HCb[x] = v;
    }
    for (int x = i; x < 512 * NN / 4; x += stride) ((unsigned*)hcT8)[x] = 0;
    for (int x = i; x < NN * HH; x += stride) Cstate[x] = 0.f;
}

// ---------------- per-step kernels ----------------

// Launch A (fused): bid < 128*Z  -> AH partials (fp8, 128x128 tiles)
//                   next 256     -> gates GEMM + LSTM elementwise (indep of P)
//                   last 16      -> out_pred(t-1) (reads previous Hupd)
__global__ __launch_bounds__(256) void k_a(
    const unsigned char* __restrict__ A8,     // [4096][4096] (x4096 scale)
    const unsigned char* __restrict__ hcT8,   // [512][4096]: h rows 0-255, c 256-511
    float* __restrict__ P, int kchunk, int Z, // P: [Z][4096][512]
    const unsigned short* __restrict__ HCb,   // [4096][KG]
    const unsigned short* __restrict__ WzTb,  // [1024][KG]
    const float* __restrict__ biasg,
    const float* __restrict__ Cstate,
    unsigned short* __restrict__ LHS3,        // [4096][1024]
    const float* __restrict__ Hupd,
    const float* __restrict__ W_out, const float* __restrict__ b_out,
    float* __restrict__ d_out, int t)
{
    __shared__ __align__(16) unsigned char smem[65536];
    const int SA  = 128 * Z;
    const int bid = blockIdx.x;
    const int tid = threadIdx.x;
    const int lane = tid & 63;
    const int wave = tid >> 6;
    const int fr = lane & 15;
    const int rq = (lane >> 4) * 4;

    if (bid < SA) {
        // ---- AH partials: (A8 @ hcT8^T) * 2^-12 ----
        f32x4 acc[4][4] = {};
        const int r    = bid & 127;
        const int col0 = (r & 3) * 128;
        const int row0 = (r >> 2) * 128;
        const int zi   = bid >> 7;
        gemm8_db(A8, hcT8, zi * kchunk, kchunk, row0, col0,
                 smem, smem + 32768, acc);
        const int wr = (wave >> 1) * 64;
        const int wc = (wave & 1) * 64;
        float* Pz = P + (size_t)zi * NN * 512;
        #pragma unroll
        for (int i = 0; i < 4; i++)
            #pragma unroll
            for (int j = 0; j < 4; j++) {
                int c = col0 + wc + j * 16 + fr;
                int rbase = row0 + wr + i * 16 + rq;
                #pragma unroll
                for (int r2 = 0; r2 < 4; r2++)
                    Pz[(size_t)(rbase + r2) * 512 + c] = acc[i][j][r2] * AINV;
            }
    } else if (bid < SA + 256) {
        // ---- gates: z = [h|x] @ Wz + b -> LSTM elementwise ----
        const int b2 = bid - SA;
        f32x4 acc[4][4] = {};
        const int row0 = (b2 >> 3) * 128;
        const int col0 = (b2 & 7) * 128;
        gemm_core_db<4>(HCb, KG, WzTb, KG, KG, row0, col0,
                        (unsigned short*)smem, (unsigned short*)(smem + 32768), acc);
        const int wr = (wave >> 1) * 64, wc = (wave & 1) * 64;
        const int g = lane & 3;
        #pragma unroll
        for (int i = 0; i < 4; i++)
            #pragma unroll
            for (int j = 0; j < 4; j++) {
                int c = col0 + wc + j * 16 + fr;
                int rbase = row0 + wr + i * 16 + rq;
                float bias = biasg[c];
                int h = c >> 2;
                #pragma unroll
                for (int r = 0; r < 4; r++) {
                    float v = acc[i][j][r] + bias;
                    float z_i = __shfl(v, (lane & ~3) | 0, 64);
                    float z_f = __shfl(v, (lane & ~3) | 1, 64);
                    float z_g = __shfl(v, (lane & ~3) | 2, 64);
                    float z_o = __shfl(v, (lane & ~3) | 3, 64);
                    if (g < 2) {
                        int n = rbase + r;
                        float cp = Cstate[n * HH + h];
                        float ccur = sigmoidf_(z_f) * cp + sigmoidf_(z_i) * tanhf_(z_g);
                        if (g == 0) {
                            float hcur = sigmoidf_(z_o) * tanhf_(ccur);
                            LHS3[(size_t)n * 1024 + h] = f2bf(hcur);
                        } else {
                            LHS3[(size_t)n * 1024 + 512 + h] = f2bf(ccur);
                        }
                    }
                }
            }
    } else {
        // ---- out_pred for step t-1 (Hupd not yet overwritten this step) ----
        if (t > 0) {
            int gid = (bid - SA - 256) * 256 + tid;       // 0..4095
            float s0 = b_out[0], s1 = b_out[1];
            const float* hp = Hupd + (size_t)gid * HH;
            #pragma unroll 8
            for (int hh = 0; hh < HH; hh++) {
                float hv = hp[hh];
                s0 += hv * W_out[hh * 2 + 0];
                s1 += hv * W_out[hh * 2 + 1];
            }
            float* o = d_out + (size_t)gid * TP + (t - 1) * PP;
            o[0] = s0; o[1] = s1;
        }
    }
}

// Launch B: SC1 = tanh(AH @ Wg + bg) -> LHS3 graph halves. 128 blocks.
__global__ __launch_bounds__(256) void k_s1(
    const float* __restrict__ P, int Zc,
    const unsigned short* __restrict__ WgT,   // [512][256]
    const float* __restrict__ bgh, const float* __restrict__ bgc,
    unsigned short* __restrict__ LHS3)
{
    __shared__ __align__(16) unsigned short As[128 * 64];
    __shared__ __align__(16) unsigned short Bs[128 * 64];
    const int r0  = blockIdx.x;
    const int tid = threadIdx.x;
    const int lane = tid & 63;
    const int wave = tid >> 6;
    const int fr = lane & 15;
    const int rq = (lane >> 4) * 4;

    const int row0 = (r0 >> 2) * 128;
    const int col0 = (r0 & 3) * 128;
    const int Aoff = (col0 < 256) ? 0 : 256;
    f32x4 acc[4][4] = {};
    const int arow = tid >> 1;
    const int kseg = (tid & 1) * 32;
    const int srow = lane >> 3, sblk = lane & 7;
    const unsigned short* Bg = WgT + (size_t)(col0 + wave*8 + srow) * 256
                                   + ((sblk ^ srow) * 8);
    unsigned short* BsW = Bs + wave * 512;
    const int fq = lane >> 4;
    const int wr = (wave >> 1) * 64, wc = (wave & 1) * 64;
    const int off0 = ((fq ^ (fr & 7)) * 8);

    for (int k0 = 0; k0 < 256; k0 += 64) {
        __syncthreads();
        #pragma unroll
        for (int q = 0; q < 4; q++)
            async16(Bg + (size_t)q * 32 * 256 + k0, BsW + q * 2048);
        // A-tile: sum partials, cvt bf16, swizzled ds_write
        const float* Pb = P + (size_t)(row0 + arow) * 512 + Aoff + k0 + kseg;
        #pragma unroll
        for (int m = 0; m < 4; m++) {
            float4 s0 = *(const float4*)(Pb + m * 8);
            float4 s1 = *(const float4*)(Pb + m * 8 + 4);
            for (int z = 1; z < Zc; z++) {
                const float* Pz = Pb + (size_t)z * NN * 512;
                float4 t0 = *(const float4*)(Pz + m * 8);
                float4 t1 = *(const float4*)(Pz + m * 8 + 4);
                s0.x += t0.x; s0.y += t0.y; s0.z += t0.z; s0.w += t0.w;
                s1.x += t1.x; s1.y += t1.y; s1.z += t1.z; s1.w += t1.w;
            }
            int pb = ((kseg >> 3) + m) ^ (arow & 7);
            short8 v;
            v[0] = (short)f2bf(s0.x); v[1] = (short)f2bf(s0.y);
            v[2] = (short)f2bf(s0.z); v[3] = (short)f2bf(s0.w);
            v[4] = (short)f2bf(s1.x); v[5] = (short)f2bf(s1.y);
            v[6] = (short)f2bf(s1.z); v[7] = (short)f2bf(s1.w);
            *(short8*)(As + arow * 64 + pb * 8) = v;
        }
        asm volatile("s_waitcnt vmcnt(0)" ::: "memory");
        __syncthreads();
        #pragma unroll
        for (int kh = 0; kh < 2; kh++) {
            const int off = off0 ^ (kh * 32);
            short8 a[4], b[4];
            #pragma unroll
            for (int i = 0; i < 4; i++)
                a[i] = *(const short8*)(As + (wr + i*16 + fr) * 64 + off);
            #pragma unroll
            for (int j = 0; j < 4; j++)
                b[j] = *(const short8*)(Bs + (wc + j*16 + fr) * 64 + off);
            #pragma unroll
            for (int i = 0; i < 4; i++)
                #pragma unroll
                for (int j = 0; j < 4; j++)
                    acc[i][j] = __builtin_amdgcn_mfma_f32_16x16x32_bf16(
                        a[i], b[j], acc[i][j], 0, 0, 0);
        }
    }
    #pragma unroll
    for (int i = 0; i < 4; i++)
        #pragma unroll
        for (int j = 0; j < 4; j++) {
            int c = col0 + wc + j * 16 + fr;              // HG col 0..511
            float bias = (c < 256) ? bgh[c] : bgc[c - 256];
            int dst = (c < 256) ? (c + 256) : (c + 512);
            int rbase = row0 + wr + i * 16 + rq;
            #pragma unroll
            for (int r = 0; r < 4; r++)
                LHS3[(size_t)(rbase + r) * 1024 + dst] =
                    f2bf(tanhf_(acc[i][j][r] + bias));
        }
}

// Launch C: U = sigmoid(LHS3 @ W2 + b) -> Hupd fp32, HCb bf16 (h),
// hcT8 fp8 (h,c), Cstate fp32 (c). Plus x_{t+1} bf16 prefetch.
__global__ __launch_bounds__(256) void k_c(
    const unsigned short* __restrict__ LHS3,
    const unsigned short* __restrict__ W2T,
    const float* __restrict__ b_h, const float* __restrict__ b_c,
    float* __restrict__ Hupd, float* __restrict__ Cstate,
    unsigned short* __restrict__ HCb, unsigned char* __restrict__ hcT8,
    const float* __restrict__ inputs, int t)
{
    __shared__ __align__(16) unsigned char smem[49152];
    f32x4 acc[2][4] = {};
    const int col0 = (blockIdx.x & 3) * 128;
    const int row0 = (blockIdx.x >> 2) * 64;
    gemm_core_db<2>(LHS3, 1024, W2T, 1024, 1024, row0, col0,
                    (unsigned short*)smem, (unsigned short*)(smem + 16384), acc);

    const int lane = threadIdx.x & 63;
    const int wave = threadIdx.x >> 6;
    const int wr = (wave >> 1) * 32;
    const int wc = (wave & 1) * 64;
    const int fr = lane & 15;
    const int rq = (lane >> 4) * 4;

    #pragma unroll
    for (int i = 0; i < 2; i++)
        #pragma unroll
        for (int j = 0; j < 4; j++) {
            int c = col0 + wc + j * 16 + fr;
            int rbase = row0 + wr + i * 16 + rq;
            float vv[4];
            if (c < 256) {
                float bias = b_h[c];
                #pragma unroll
                for (int r = 0; r < 4; r++) {
                    int n = rbase + r;
                    float v = sigmoidf_(acc[i][j][r] + bias);
                    vv[r] = v;
                    Hupd[(size_t)n * HH + c] = v;
                    HCb[(size_t)n * KG + c] = f2bf(v);
                }
                unsigned pk = (unsigned)f2e4m3(vv[0]) | ((unsigned)f2e4m3(vv[1]) << 8)
                            | ((unsigned)f2e4m3(vv[2]) << 16) | ((unsigned)f2e4m3(vv[3]) << 24);
                *(unsigned*)(hcT8 + (size_t)c * NN + rbase) = pk;
            } else {
                int c2 = c - 256;
                float bias = b_c[c2];
                #pragma unroll
                for (int r = 0; r < 4; r++) {
                    int n = rbase + r;
                    float v = sigmoidf_(acc[i][j][r] + bias);
                    vv[r] = v;
                    Cstate[(size_t)n * HH + c2] = v;
                }
                unsigned pk = (unsigned)f2e4m3(vv[0]) | ((unsigned)f2e4m3(vv[1]) << 8)
                            | ((unsigned)f2e4m3(vv[2]) << 16) | ((unsigned)f2e4m3(vv[3]) << 24);
                *(unsigned*)(hcT8 + (size_t)(256 + c2) * NN + rbase) = pk;
            }
        }

    int gid = blockIdx.x * 256 + threadIdx.x;             // 0..65535
    if (t + 1 < TT) {
        int n = gid >> 4, d = gid & 15;
        HCb[(size_t)n * KG + 256 + d] = f2bf(inputs[(size_t)n * TD + (t + 1) * DD + d]);
    }
}

// final out_pred for t = T-1
__global__ __launch_bounds__(256) void k_out(
    const float* __restrict__ Hupd, const float* __restrict__ W_out,
    const float* __restrict__ b_out, float* __restrict__ d_out, int t)
{
    int n = blockIdx.x * blockDim.x + threadIdx.x;
    if (n >= NN) return;
    float s0 = b_out[0], s1 = b_out[1];
    const float* hp = Hupd + (size_t)n * HH;
    #pragma unroll 8
    for (int hh = 0; hh < HH; hh++) {
        float hv = hp[hh];
        s0 += hv * W_out[hh * 2 + 0];
        s1 += hv * W_out[hh * 2 + 1];
    }
    float* o = d_out + (size_t)n * TP + t * PP;
    o[0] = s0; o[1] = s1;
}

extern "C" void kernel_launch(void* const* d_in, const int* in_sizes, int n_in,
                              void* d_out_v, int out_size, void* d_ws, size_t ws_size,
                              hipStream_t stream)
{
    const float* inputs = (const float*)d_in[0];
    const float* A      = (const float*)d_in[1];
    const float* kern   = (const float*)d_in[2];
    const float* rk     = (const float*)d_in[3];
    const float* lb     = (const float*)d_in[4];
    const float* Wgh    = (const float*)d_in[5];
    const float* bgh    = (const float*)d_in[6];
    const float* Wgc    = (const float*)d_in[7];
    const float* bgc    = (const float*)d_in[8];
    const float* Whc    = (const float*)d_in[9];
    const float* Whp    = (const float*)d_in[10];
    const float* bh     = (const float*)d_in[11];
    const float* Wcc    = (const float*)d_in[12];
    const float* Wcp    = (const float*)d_in[13];
    const float* bc     = (const float*)d_in[14];
    const float* Wout   = (const float*)d_in[15];
    const float* bout   = (const float*)d_in[16];
    float* d_out = (float*)d_out_v;

    char* ws = (char*)d_ws;
    size_t off = 0;
    auto alloc = [&](size_t bytes) {
        char* p = ws + off;
        off += (bytes + 255) & ~(size_t)255;
        return p;
    };
    unsigned char*  A8    = (unsigned char*) alloc((size_t)NN * NN);           // 16 MB
    unsigned char*  hcT8  = (unsigned char*) alloc((size_t)512 * NN);          // 2 MB
    unsigned short* HCb   = (unsigned short*)alloc((size_t)NN * KG * 2);       // 2.5 MB
    unsigned short* WzTb  = (unsigned short*)alloc((size_t)1024 * KG * 2);
    unsigned short* WgT   = (unsigned short*)alloc((size_t)512 * 256 * 2);
    unsigned short* W2T   = (unsigned short*)alloc((size_t)512 * 1024 * 2);
    float*          biasg = (float*)         alloc(1024 * 4);
    unsigned short* LHS3  = (unsigned short*)alloc((size_t)NN * 1024 * 2);     // 8 MB
    float*          Cst   = (float*)         alloc((size_t)NN * HH * 4);       // 4 MB
    float*          Hupd  = (float*)         alloc((size_t)NN * HH * 4);       // 4 MB
    const size_t PB = (size_t)NN * 512 * 4;                                    // 8 MB
    int Z = (ws_size >= off + 2 * PB + 1024) ? 2 : 1;
    float* P = (float*)alloc((size_t)Z * PB);
    int kchunk = NN / Z;
    int SA = 128 * Z;
    (void)in_sizes; (void)n_in; (void)out_size;

    k_prep_a<<<2048, 256, 0, stream>>>(A, A8);
    k_prep_w<<<256, 256, 0, stream>>>(Wgh, Wgc, rk, kern, lb,
                                      Whc, Whp, Wcc, Wcp, WzTb, WgT, W2T, biasg);
    k_prep_s<<<512, 256, 0, stream>>>(inputs, HCb, hcT8, Cst);

    for (int t = 0; t < TT; t++) {
        k_a<<<SA + 272, 256, 0, stream>>>(A8, hcT8, P, kchunk, Z,
                                          HCb, WzTb, biasg, Cst, LHS3,
                                          Hupd, Wout, bout, d_out, t);
        k_s1<<<128, 256, 0, stream>>>(P, Z, WgT, bgh, bgc, LHS3);
        k_c<<<256, 256, 0, stream>>>(LHS3, W2T, bh, bc, Hupd, Cst, HCb, hcT8,
                                     inputs, t);
    }
    k_out<<<16, 256, 0, stream>>>(Hupd, Wout, bout, d_out, TT - 1);
}

// Round 2
// 24534.875 us; speedup vs baseline: 1.2252x; 1.1760x over previous
//
#include <hip/hip_runtime.h>

using short8 = __attribute__((ext_vector_type(8))) short;
using f32x4  = __attribute__((ext_vector_type(4))) float;

#define NN 4096
#define TT 365
#define DD 16
#define HH 256
#define PP 2
#define TD (TT*DD)      // 5840
#define TP (TT*PP)      // 730
#define KG 320          // gates K: [h(256) | x(16) | pad(48)]
#define ASCALE 4096.0f
#define HWSCALE 64.0f
#define AINV2 (1.0f/(4096.0f*64.0f))   // A8 scale * hwT8 scale

__device__ __forceinline__ unsigned short f2bf(float f) {
    union { float f; unsigned u; } v; v.f = f;
    unsigned r = v.u + 0x7FFFu + ((v.u >> 16) & 1u);   // RNE
    return (unsigned short)(r >> 16);
}
// float -> OCP e4m3fn, RNE, saturating at 448
__device__ __forceinline__ unsigned char f2e4m3(float f) {
    union { float f; unsigned u; } v; v.f = f;
    unsigned s = (v.u >> 24) & 0x80u;
    unsigned au = v.u & 0x7fffffffu;
    if (au >= 0x43E00000u) return (unsigned char)(s | 0x7E);   // >=448 -> 448
    if (au < 0x3C800000u) {                                    // <2^-6: subnormal
        int m = __float2int_rn(__uint_as_float(au) * 512.0f);  // 0..8
        return (unsigned char)(s | (unsigned)m);
    }
    unsigned r = au + 0x7FFFFu + ((au >> 20) & 1u);            // RNE to 3 mantissa bits
    return (unsigned char)(s | ((r >> 20) - 0x3C0u));
}
__device__ __forceinline__ float sigmoidf_(float x) {
    return 1.0f / (1.0f + __expf(-x));
}
__device__ __forceinline__ float tanhf_(float x) {
    float t = __expf(2.0f * x);
    return (t - 1.0f) / (t + 1.0f);
}
__device__ __forceinline__ void async16(const void* g, void* l) {
    __builtin_amdgcn_global_load_lds(
        (const __attribute__((address_space(1))) void*)g,
        (__attribute__((address_space(3))) void*)l, 16, 0, 0);
}

// ---------------------------------------------------------------------------
// bf16 core, double-buffered: 256 thr = 4 waves 2x2. BN=128, BK=64, BM=32*TI.
// C = Amat(row-major,lda) @ Bt^T (Bt[col][k],ldb). 16B-block XOR swizzle.
// C frag: col = lane&15, row = (lane>>4)*4 + reg.
// As: 2 * TI*32*64 shorts.  Bs: 2 * 128*64 shorts.
// ---------------------------------------------------------------------------
template<int TI>
__device__ __forceinline__ void gemm_core_db(
    const unsigned short* __restrict__ Amat, int lda,
    const unsigned short* __restrict__ Bt,  int ldb,
    int k_len, int row0, int col0,
    unsigned short* As, unsigned short* Bs,
    f32x4 (&acc)[TI][4])
{
    const int tid  = threadIdx.x;
    const int lane = tid & 63;
    const int wave = tid >> 6;
    const int srow = lane >> 3;
    const int sblk = lane & 7;
    const int ABUF = TI * 32 * 64;     // shorts per A buffer
    const int BBUF = 128 * 64;         // shorts per B buffer

    const unsigned short* Ag = Amat + (size_t)(row0 + wave*8 + srow) * lda
                                    + ((sblk ^ srow) * 8);
    const unsigned short* Bg = Bt   + (size_t)(col0 + wave*8 + srow) * ldb
                                    + ((sblk ^ srow) * 8);

    const int fr = lane & 15;
    const int fq = lane >> 4;
    const int wr = (wave >> 1) * (TI * 16);
    const int wc = (wave & 1) * 64;
    const int off0 = ((fq ^ (fr & 7)) * 8);

    // prologue: stage tile 0 into buffer 0
    {
        unsigned short* AsW = As + wave * 512;
        unsigned short* BsW = Bs + wave * 512;
        #pragma unroll
        for (int q = 0; q < TI; q++) async16(Ag + (size_t)q * 32 * lda, AsW + q * 2048);
        #pragma unroll
        for (int q = 0; q < 4;  q++) async16(Bg + (size_t)q * 32 * ldb, BsW + q * 2048);
    }
    asm volatile("s_waitcnt vmcnt(0)" ::: "memory");
    __syncthreads();

    const int nk = k_len >> 6;
    int sel = 0;
    for (int it = 0; it < nk; ++it) {
        if (it + 1 < nk) {   // prefetch next tile into other buffer
            const unsigned short* Agn = Ag + (it + 1) * 64;
            const unsigned short* Bgn = Bg + (it + 1) * 64;
            unsigned short* AsW = As + (sel ^ 1) * ABUF + wave * 512;
            unsigned short* BsW = Bs + (sel ^ 1) * BBUF + wave * 512;
            #pragma unroll
            for (int q = 0; q < TI; q++) async16(Agn + (size_t)q * 32 * lda, AsW + q * 2048);
            #pragma unroll
            for (int q = 0; q < 4;  q++) async16(Bgn + (size_t)q * 32 * ldb, BsW + q * 2048);
        }
        const unsigned short* Ab = As + sel * ABUF;
        const unsigned short* Bb = Bs + sel * BBUF;
        #pragma unroll
        for (int kh = 0; kh < 2; kh++) {
            const int off = off0 ^ (kh * 32);
            short8 a[TI], b[4];
            #pragma unroll
            for (int i = 0; i < TI; i++)
                a[i] = *(const short8*)(Ab + (wr + i*16 + fr) * 64 + off);
            #pragma unroll
            for (int j = 0; j < 4;  j++)
                b[j] = *(const short8*)(Bb + (wc + j*16 + fr) * 64 + off);
            #pragma unroll
            for (int i = 0; i < TI; i++)
                #pragma unroll
                for (int j = 0; j < 4; j++)
                    acc[i][j] = __builtin_amdgcn_mfma_f32_16x16x32_bf16(
                        a[i], b[j], acc[i][j], 0, 0, 0);
        }
        asm volatile("s_waitcnt vmcnt(0)" ::: "memory");  // prefetch landed
        __syncthreads();                                   // all reads of sel done
        sel ^= 1;
    }
}

// ---------------------------------------------------------------------------
// fp8 core, double-buffered, BM=32*TI x 128 tile: C = A8 @ B8^T, both
// row-major [*][NN] bytes, BK=128. As: 2*TI*32*128 B.  Bs: 2*128*128 B.
// ---------------------------------------------------------------------------
template<int TI>
__device__ __forceinline__ void gemm8_db(
    const unsigned char* __restrict__ Amat,
    const unsigned char* __restrict__ Bmat,
    int kb, int klen, int row0, int col0,
    unsigned char* As, unsigned char* Bs,
    f32x4 (&acc)[TI][4])
{
    const int tid  = threadIdx.x;
    const int lane = tid & 63;
    const int wave = tid >> 6;
    const int srow = lane >> 3;
    const int sblk = lane & 7;
    const int ABUF = TI * 32 * 128;
    const int BBUF = 128 * 128;

    const unsigned char* Ag = Amat + (size_t)(row0 + wave*8 + srow) * NN
                                   + ((sblk ^ srow) * 16) + kb;
    const unsigned char* Bg = Bmat + (size_t)(col0 + wave*8 + srow) * NN
                                   + ((sblk ^ srow) * 16) + kb;

    const int fr = lane & 15;
    const int fq = lane >> 4;
    const int wr = (wave >> 1) * (TI * 16);
    const int wc = (wave & 1) * 64;
    int offk[4];
    #pragma unroll
    for (int kq = 0; kq < 4; kq++)
        offk[kq] = (((kq*2 + (fq >> 1)) ^ (fr & 7)) << 4) + ((fq & 1) << 3);

    {
        unsigned char* AsW = As + wave * 1024;
        unsigned char* BsW = Bs + wave * 1024;
        #pragma unroll
        for (int q = 0; q < TI; q++) async16(Ag + (size_t)q * 32 * NN, AsW + q * 4096);
        #pragma unroll
        for (int q = 0; q < 4;  q++) async16(Bg + (size_t)q * 32 * NN, BsW + q * 4096);
    }
    asm volatile("s_waitcnt vmcnt(0)" ::: "memory");
    __syncthreads();

    const int nk = klen >> 7;
    int sel = 0;
    for (int it = 0; it < nk; ++it) {
        if (it + 1 < nk) {
            const unsigned char* Agn = Ag + (size_t)(it + 1) * 128;
            const unsigned char* Bgn = Bg + (size_t)(it + 1) * 128;
            unsigned char* AsW = As + (sel ^ 1) * ABUF + wave * 1024;
            unsigned char* BsW = Bs + (sel ^ 1) * BBUF + wave * 1024;
            #pragma unroll
            for (int q = 0; q < TI; q++) async16(Agn + (size_t)q * 32 * NN, AsW + q * 4096);
            #pragma unroll
            for (int q = 0; q < 4;  q++) async16(Bgn + (size_t)q * 32 * NN, BsW + q * 4096);
        }
        const unsigned char* Ab = As + sel * ABUF;
        const unsigned char* Bb = Bs + sel * BBUF;
        #pragma unroll
        for (int kq = 0; kq < 4; kq++) {
            long a[TI], b[4];
            #pragma unroll
            for (int i = 0; i < TI; i++) a[i] = *(const long*)(Ab + (wr + i*16 + fr) * 128 + offk[kq]);
            #pragma unroll
            for (int j = 0; j < 4;  j++) b[j] = *(const long*)(Bb + (wc + j*16 + fr) * 128 + offk[kq]);
            #pragma unroll
            for (int i = 0; i < TI; i++)
                #pragma unroll
                for (int j = 0; j < 4; j++)
                    acc[i][j] = __builtin_amdgcn_mfma_f32_16x16x32_fp8_fp8(
                        a[i], b[j], acc[i][j], 0, 0, 0);
        }
        asm volatile("s_waitcnt vmcnt(0)" ::: "memory");
        __syncthreads();
        sel ^= 1;
    }
}

// ---------------- prep (once per launch) ----------------

__global__ __launch_bounds__(256) void k_prep_a(const float* __restrict__ A,
                                                unsigned char* __restrict__ A8) {
    size_t i = (size_t)blockIdx.x * blockDim.x + threadIdx.x;
    size_t stride = (size_t)gridDim.x * blockDim.x;
    size_t total = (size_t)NN * NN / 4;
    for (; i < total; i += stride) {
        float4 v = ((const float4*)A)[i];
        unsigned pk = (unsigned)f2e4m3(v.x * ASCALE)
                    | ((unsigned)f2e4m3(v.y * ASCALE) << 8)
                    | ((unsigned)f2e4m3(v.z * ASCALE) << 16)
                    | ((unsigned)f2e4m3(v.w * ASCALE) << 24);
        ((unsigned*)A8)[i] = pk;
    }
}

// WzTb[col][k] col 0..1023 gate-interleaved (c2=4h+g, oc=g*256+h):
//   k<256 -> rkernel[k][oc]; 256<=k<272 -> kernel[k-256][oc]; else 0
// WgT[col][k] col 0..511, k 0..255: col<256 -> Wgh[k][col] else Wgc[k][col-256]
// WU[col][k]  col 0..511, k 0..511:
//   col<256 (h_upd): k<256 -> Whc[k][col],     k>=256 -> Whp[k-256][col]
//   col>=256 (c_upd): k<256 -> Wcc[k][col-256], k>=256 -> Wcp[k-256][col-256]
__global__ __launch_bounds__(256) void k_prep_w(
    const float* __restrict__ Wgh, const float* __restrict__ Wgc,
    const float* __restrict__ rk,  const float* __restrict__ kern,
    const float* __restrict__ lb,
    const float* __restrict__ Whc, const float* __restrict__ Whp,
    const float* __restrict__ Wcc, const float* __restrict__ Wcp,
    unsigned short* __restrict__ WzTb, unsigned short* __restrict__ WgT,
    unsigned short* __restrict__ WU, float* __restrict__ biasg)
{
    int i = blockIdx.x * blockDim.x + threadIdx.x;
    int stride = gridDim.x * blockDim.x;
    for (int x = i; x < 1024 * KG; x += stride) {
        int col = x / KG, k = x % KG;
        int oc = (col & 3) * 256 + (col >> 2);
        float val = 0.f;
        if (k < 256) val = rk[k * 1024 + oc];
        else if (k < 272) val = kern[(k - 256) * 1024 + oc];
        WzTb[x] = f2bf(val);
    }
    for (int x = i; x < 512 * 256; x += stride) {
        int col = x >> 8, k = x & 255;
        float val = (col < 256) ? Wgh[k * 256 + col] : Wgc[k * 256 + (col - 256)];
        WgT[x] = f2bf(val);
    }
    for (int x = i; x < 512 * 512; x += stride) {
        int col = x >> 9, k = x & 511;
        float val;
        if (col < 256)
            val = (k < 256) ? Whc[k * 256 + col] : Whp[(k - 256) * 256 + col];
        else {
            int c2 = col - 256;
            val = (k < 256) ? Wcc[k * 256 + c2] : Wcp[(k - 256) * 256 + c2];
        }
        WU[x] = f2bf(val);
    }
    for (int x = i; x < 1024; x += stride)
        biasg[x] = lb[(x & 3) * 256 + (x >> 2)];
}

// HCb[n][KG]: 0..255 h_prev bf16, 256..271 x_t, rest 0. hwT8, Cstate zeroed.
__global__ __launch_bounds__(256) void k_prep_s(const float* __restrict__ inputs,
                                                unsigned short* __restrict__ HCb,
                                                unsigned char* __restrict__ hwT8,
                                                float* __restrict__ Cstate)
{
    int i = blockIdx.x * blockDim.x + threadIdx.x;
    int stride = gridDim.x * blockDim.x;
    for (int x = i; x < NN * KG; x += stride) {
        int n = x / KG, col = x % KG;
        unsigned short v = 0;
        if (col >= 256 && col < 272)
            v = f2bf(inputs[(size_t)n * TD + (col - 256)]);
        HCb[x] = v;
    }
    for (int x = i; x < 512 * NN / 4; x += stride) ((unsigned*)hwT8)[x] = 0;
    for (int x = i; x < NN * HH; x += stride) Cstate[x] = 0.f;
}

// ---------------- per-step kernels ----------------

// kA: bid<256 -> graph states: tanh(A8 @ hwT8^T * AINV2 + bg) -> LHS3 graph cols
//     bid>=256 -> gates GEMM + LSTM elementwise -> LHS3 cur cols
// LHS3 layout: [h_cur(0-255) | h_graph(256-511) | c_cur(512-767) | c_graph(768-1023)]
__global__ __launch_bounds__(256) void k_a(
    const unsigned char* __restrict__ A8,     // [4096][4096] (x4096 scale)
    const unsigned char* __restrict__ hwT8,   // [512][4096]: HWh rows 0-255, HWc 256-511 (x64)
    const float* __restrict__ bgh, const float* __restrict__ bgc,
    const unsigned short* __restrict__ HCb,   // [4096][KG]
    const unsigned short* __restrict__ WzTb,  // [1024][KG]
    const float* __restrict__ biasg,
    const float* __restrict__ Cstate,
    unsigned short* __restrict__ LHS3)        // [4096][1024]
{
    __shared__ __align__(16) unsigned char smem[65536];
    const int bid = blockIdx.x;
    const int tid = threadIdx.x;
    const int lane = tid & 63;
    const int wave = tid >> 6;
    const int fr = lane & 15;
    const int rq = (lane >> 4) * 4;

    if (bid < 256) {
        // ---- graph: G = tanh(A8 @ hwT8^T * AINV2 + bias), 64x128 tiles ----
        f32x4 acc[2][4] = {};
        const int row0 = (bid >> 2) * 64;
        const int col0 = (bid & 3) * 128;
        gemm8_db<2>(A8, hwT8, 0, NN, row0, col0, smem, smem + 16384, acc);
        const int wr = (wave >> 1) * 32;
        const int wc = (wave & 1) * 64;
        #pragma unroll
        for (int i = 0; i < 2; i++)
            #pragma unroll
            for (int j = 0; j < 4; j++) {
                int c = col0 + wc + j * 16 + fr;          // HW col 0..511
                float bias = (c < 256) ? bgh[c] : bgc[c - 256];
                int dst = (c < 256) ? (c + 256) : (c + 512);
                int rbase = row0 + wr + i * 16 + rq;
                #pragma unroll
                for (int r = 0; r < 4; r++)
                    LHS3[(size_t)(rbase + r) * 1024 + dst] =
                        f2bf(tanhf_(acc[i][j][r] * AINV2 + bias));
            }
    } else {
        // ---- gates: z = [h|x] @ Wz + b -> LSTM elementwise ----
        const int b2 = bid - 256;
        f32x4 acc[4][4] = {};
        const int row0 = (b2 >> 3) * 128;
        const int col0 = (b2 & 7) * 128;
        gemm_core_db<4>(HCb, KG, WzTb, KG, KG, row0, col0,
                        (unsigned short*)smem, (unsigned short*)(smem + 32768), acc);
        const int wr = (wave >> 1) * 64, wc = (wave & 1) * 64;
        const int g = lane & 3;
        #pragma unroll
        for (int i = 0; i < 4; i++)
            #pragma unroll
            for (int j = 0; j < 4; j++) {
                int c = col0 + wc + j * 16 + fr;
                int rbase = row0 + wr + i * 16 + rq;
                float bias = biasg[c];
                int h = c >> 2;
                #pragma unroll
                for (int r = 0; r < 4; r++) {
                    float v = acc[i][j][r] + bias;
                    float z_i = __shfl(v, (lane & ~3) | 0, 64);
                    float z_f = __shfl(v, (lane & ~3) | 1, 64);
                    float z_g = __shfl(v, (lane & ~3) | 2, 64);
                    float z_o = __shfl(v, (lane & ~3) | 3, 64);
                    if (g < 2) {
                        int n = rbase + r;
                        float cp = Cstate[n * HH + h];
                        float ccur = sigmoidf_(z_f) * cp + sigmoidf_(z_i) * tanhf_(z_g);
                        if (g == 0) {
                            float hcur = sigmoidf_(z_o) * tanhf_(ccur);
                            LHS3[(size_t)n * 1024 + h] = f2bf(hcur);
                        } else {
                            LHS3[(size_t)n * 1024 + 512 + h] = f2bf(ccur);
                        }
                    }
                }
            }
    }
}

// kU: U = sigmoid(LHS3[:,off:off+512] @ WU + b)  (K=512, no zero blocks)
// -> Hupd f32, HCb bf16 (h), UB bf16 [4096][512], Cstate f32 (c).
// Plus x_{t+1} bf16 prefetch into HCb.
__global__ __launch_bounds__(256) void k_u(
    const unsigned short* __restrict__ LHS3,
    const unsigned short* __restrict__ WU,    // [512][512]
    const float* __restrict__ b_h, const float* __restrict__ b_c,
    float* __restrict__ Hupd, float* __restrict__ Cstate,
    unsigned short* __restrict__ HCb, unsigned short* __restrict__ UB,
    const float* __restrict__ inputs, int t)
{
    __shared__ __align__(16) unsigned char smem[49152];
    f32x4 acc[2][4] = {};
    const int col0 = (blockIdx.x & 3) * 128;          // U col 0..511
    const int row0 = (blockIdx.x >> 2) * 64;
    const unsigned short* Am = LHS3 + ((col0 < 256) ? 0 : 512);
    gemm_core_db<2>(Am, 1024, WU, 512, 512, row0, col0,
                    (unsigned short*)smem, (unsigned short*)(smem + 16384), acc);

    const int lane = threadIdx.x & 63;
    const int wave = threadIdx.x >> 6;
    const int wr = (wave >> 1) * 32;
    const int wc = (wave & 1) * 64;
    const int fr = lane & 15;
    const int rq = (lane >> 4) * 4;

    #pragma unroll
    for (int i = 0; i < 2; i++)
        #pragma unroll
        for (int j = 0; j < 4; j++) {
            int c = col0 + wc + j * 16 + fr;
            int rbase = row0 + wr + i * 16 + rq;
            if (c < 256) {
                float bias = b_h[c];
                #pragma unroll
                for (int r = 0; r < 4; r++) {
                    int n = rbase + r;
                    float v = sigmoidf_(acc[i][j][r] + bias);
                    Hupd[(size_t)n * HH + c] = v;
                    HCb[(size_t)n * KG + c] = f2bf(v);
                    UB[(size_t)n * 512 + c] = f2bf(v);
                }
            } else {
                int c2 = c - 256;
                float bias = b_c[c2];
                #pragma unroll
                for (int r = 0; r < 4; r++) {
                    int n = rbase + r;
                    float v = sigmoidf_(acc[i][j][r] + bias);
                    Cstate[(size_t)n * HH + c2] = v;
                    UB[(size_t)n * 512 + c] = f2bf(v);
                }
            }
        }

    int gid = blockIdx.x * 256 + threadIdx.x;             // 0..65535
    if (t + 1 < TT) {
        int n = gid >> 4, d = gid & 15;
        HCb[(size_t)n * KG + 256 + d] = f2bf(inputs[(size_t)n * TD + (t + 1) * DD + d]);
    }
}

// kHW: bid<256 -> HW = UB @ WgT^T (K=256, A-offset selects Uh/Uc), x64 -> fp8
//               transposed store hwT8[col][n] for next step's kA.
//      bid>=256 -> out_pred(t) from Hupd.
__global__ __launch_bounds__(256) void k_hw(
    const unsigned short* __restrict__ UB,    // [4096][512] = [Uh|Uc] bf16
    const unsigned short* __restrict__ WgT,   // [512][256]
    unsigned char* __restrict__ hwT8,         // [512][4096]
    const float* __restrict__ Hupd,
    const float* __restrict__ W_out, const float* __restrict__ b_out,
    float* __restrict__ d_out, int t)
{
    __shared__ __align__(16) unsigned char smem[49152];
    const int bid = blockIdx.x;
    const int tid = threadIdx.x;

    if (bid < 256) {
        f32x4 acc[2][4] = {};
        const int row0 = (bid >> 2) * 64;
        const int col0 = (bid & 3) * 128;                 // HW col 0..511
        const unsigned short* Am = UB + ((col0 < 256) ? 0 : 256);
        gemm_core_db<2>(Am, 512, WgT, 256, 256, row0, col0,
                        (unsigned short*)smem, (unsigned short*)(smem + 16384), acc);

        const int lane = tid & 63;
        const int wave = tid >> 6;
        const int wr = (wave >> 1) * 32;
        const int wc = (wave & 1) * 64;
        const int fr = lane & 15;
        const int rq = (lane >> 4) * 4;
        #pragma unroll
        for (int i = 0; i < 2; i++)
            #pragma unroll
            for (int j = 0; j < 4; j++) {
                int c = col0 + wc + j * 16 + fr;
                int rbase = row0 + wr + i * 16 + rq;
                unsigned pk = (unsigned)f2e4m3(acc[i][j][0] * HWSCALE)
                            | ((unsigned)f2e4m3(acc[i][j][1] * HWSCALE) << 8)
                            | ((unsigned)f2e4m3(acc[i][j][2] * HWSCALE) << 16)
                            | ((unsigned)f2e4m3(acc[i][j][3] * HWSCALE) << 24);
                *(unsigned*)(hwT8 + (size_t)c * NN + rbase) = pk;
            }
    } else {
        int gid = (bid - 256) * 256 + tid;                // 0..4095
        float s0 = b_out[0], s1 = b_out[1];
        const float* hp = Hupd + (size_t)gid * HH;
        #pragma unroll 8
        for (int hh = 0; hh < HH; hh++) {
            float hv = hp[hh];
            s0 += hv * W_out[hh * 2 + 0];
            s1 += hv * W_out[hh * 2 + 1];
        }
        float* o = d_out + (size_t)gid * TP + t * PP;
        o[0] = s0; o[1] = s1;
    }
}

extern "C" void kernel_launch(void* const* d_in, const int* in_sizes, int n_in,
                              void* d_out_v, int out_size, void* d_ws, size_t ws_size,
                              hipStream_t stream)
{
    const float* inputs = (const float*)d_in[0];
    const float* A      = (const float*)d_in[1];
    const float* kern   = (const float*)d_in[2];
    const float* rk     = (const float*)d_in[3];
    const float* lb     = (const float*)d_in[4];
    const float* Wgh    = (const float*)d_in[5];
    const float* bgh    = (const float*)d_in[6];
    const float* Wgc    = (const float*)d_in[7];
    const float* bgc    = (const float*)d_in[8];
    const float* Whc    = (const float*)d_in[9];
    const float* Whp    = (const float*)d_in[10];
    const float* bh     = (const float*)d_in[11];
    const float* Wcc    = (const float*)d_in[12];
    const float* Wcp    = (const float*)d_in[13];
    const float* bc     = (const float*)d_in[14];
    const float* Wout   = (const float*)d_in[15];
    const float* bout   = (const float*)d_in[16];
    float* d_out = (float*)d_out_v;

    char* ws = (char*)d_ws;
    size_t off = 0;
    auto alloc = [&](size_t bytes) {
        char* p = ws + off;
        off += (bytes + 255) & ~(size_t)255;
        return p;
    };
    unsigned char*  A8    = (unsigned char*) alloc((size_t)NN * NN);           // 16 MB
    unsigned char*  hwT8  = (unsigned char*) alloc((size_t)512 * NN);          // 2 MB
    unsigned short* HCb   = (unsigned short*)alloc((size_t)NN * KG * 2);       // 2.5 MB
    unsigned short* WzTb  = (unsigned short*)alloc((size_t)1024 * KG * 2);
    unsigned short* WgT   = (unsigned short*)alloc((size_t)512 * 256 * 2);
    unsigned short* WU    = (unsigned short*)alloc((size_t)512 * 512 * 2);
    float*          biasg = (float*)         alloc(1024 * 4);
    unsigned short* LHS3  = (unsigned short*)alloc((size_t)NN * 1024 * 2);     // 8 MB
    float*          Cst   = (float*)         alloc((size_t)NN * HH * 4);       // 4 MB
    float*          Hupd  = (float*)         alloc((size_t)NN * HH * 4);       // 4 MB
    unsigned short* UB    = (unsigned short*)alloc((size_t)NN * 512 * 2);      // 4 MB
    (void)in_sizes; (void)n_in; (void)out_size; (void)ws_size;

    k_prep_a<<<2048, 256, 0, stream>>>(A, A8);
    k_prep_w<<<256, 256, 0, stream>>>(Wgh, Wgc, rk, kern, lb,
                                      Whc, Whp, Wcc, Wcp, WzTb, WgT, WU, biasg);
    k_prep_s<<<512, 256, 0, stream>>>(inputs, HCb, hwT8, Cst);

    for (int t = 0; t < TT; t++) {
        k_a<<<512, 256, 0, stream>>>(A8, hwT8, bgh, bgc,
                                     HCb, WzTb, biasg, Cst, LHS3);
        k_u<<<256, 256, 0, stream>>>(LHS3, WU, bh, bc, Hupd, Cst, HCb, UB,
                                     inputs, t);
        k_hw<<<272, 256, 0, stream>>>(UB, WgT, hwT8, Hupd, Wout, bout, d_out, t);
    }
}

// Round 3
// 22334.245 us; speedup vs baseline: 1.3460x; 1.0985x over previous
//
#include <hip/hip_runtime.h>

using short8 = __attribute__((ext_vector_type(8))) short;
using f32x4  = __attribute__((ext_vector_type(4))) float;

#define NN 4096
#define TT 365
#define DD 16
#define HH 256
#define PP 2
#define TD (TT*DD)      // 5840
#define TP (TT*PP)      // 730
#define KG 320          // gates K: [h(256) | x(16) | pad(48)]
#define ASCALE 4096.0f
#define HWSCALE 64.0f
#define AINV2 (1.0f/(4096.0f*64.0f))   // A8 scale * hwT8 scale

__device__ __forceinline__ unsigned short f2bf(float f) {
    union { float f; unsigned u; } v; v.f = f;
    unsigned r = v.u + 0x7FFFu + ((v.u >> 16) & 1u);   // RNE
    return (unsigned short)(r >> 16);
}
// float -> OCP e4m3fn, RNE, saturating at 448
__device__ __forceinline__ unsigned char f2e4m3(float f) {
    union { float f; unsigned u; } v; v.f = f;
    unsigned s = (v.u >> 24) & 0x80u;
    unsigned au = v.u & 0x7fffffffu;
    if (au >= 0x43E00000u) return (unsigned char)(s | 0x7E);   // >=448 -> 448
    if (au < 0x3C800000u) {                                    // <2^-6: subnormal
        int m = __float2int_rn(__uint_as_float(au) * 512.0f);  // 0..8
        return (unsigned char)(s | (unsigned)m);
    }
    unsigned r = au + 0x7FFFFu + ((au >> 20) & 1u);            // RNE to 3 mantissa bits
    return (unsigned char)(s | ((r >> 20) - 0x3C0u));
}
__device__ __forceinline__ float sigmoidf_(float x) {
    return 1.0f / (1.0f + __expf(-x));
}
__device__ __forceinline__ float tanhf_(float x) {
    float t = __expf(2.0f * x);
    return (t - 1.0f) / (t + 1.0f);
}
__device__ __forceinline__ void async16(const void* g, void* l) {
    __builtin_amdgcn_global_load_lds(
        (const __attribute__((address_space(1))) void*)g,
        (__attribute__((address_space(3))) void*)l, 16, 0, 0);
}

// ---------------------------------------------------------------------------
// bf16 core, double-buffered: 256 thr = 4 waves 2x2. BN=128, BK=64, BM=32*TI.
// C = Amat(row-major,lda) @ Bt^T (Bt[col][k],ldb). 16B-block XOR swizzle.
// C frag: col = lane&15, row = (lane>>4)*4 + reg.
// ---------------------------------------------------------------------------
template<int TI>
__device__ __forceinline__ void gemm_core_db(
    const unsigned short* __restrict__ Amat, int lda,
    const unsigned short* __restrict__ Bt,  int ldb,
    int k_len, int row0, int col0,
    unsigned short* As, unsigned short* Bs,
    f32x4 (&acc)[TI][4])
{
    const int tid  = threadIdx.x;
    const int lane = tid & 63;
    const int wave = tid >> 6;
    const int srow = lane >> 3;
    const int sblk = lane & 7;
    const int ABUF = TI * 32 * 64;     // shorts per A buffer
    const int BBUF = 128 * 64;         // shorts per B buffer

    const unsigned short* Ag = Amat + (size_t)(row0 + wave*8 + srow) * lda
                                    + ((sblk ^ srow) * 8);
    const unsigned short* Bg = Bt   + (size_t)(col0 + wave*8 + srow) * ldb
                                    + ((sblk ^ srow) * 8);

    const int fr = lane & 15;
    const int fq = lane >> 4;
    const int wr = (wave >> 1) * (TI * 16);
    const int wc = (wave & 1) * 64;
    const int off0 = ((fq ^ (fr & 7)) * 8);

    {
        unsigned short* AsW = As + wave * 512;
        unsigned short* BsW = Bs + wave * 512;
        #pragma unroll
        for (int q = 0; q < TI; q++) async16(Ag + (size_t)q * 32 * lda, AsW + q * 2048);
        #pragma unroll
        for (int q = 0; q < 4;  q++) async16(Bg + (size_t)q * 32 * ldb, BsW + q * 2048);
    }
    asm volatile("s_waitcnt vmcnt(0)" ::: "memory");
    __syncthreads();

    const int nk = k_len >> 6;
    int sel = 0;
    for (int it = 0; it < nk; ++it) {
        if (it + 1 < nk) {
            const unsigned short* Agn = Ag + (it + 1) * 64;
            const unsigned short* Bgn = Bg + (it + 1) * 64;
            unsigned short* AsW = As + (sel ^ 1) * ABUF + wave * 512;
            unsigned short* BsW = Bs + (sel ^ 1) * BBUF + wave * 512;
            #pragma unroll
            for (int q = 0; q < TI; q++) async16(Agn + (size_t)q * 32 * lda, AsW + q * 2048);
            #pragma unroll
            for (int q = 0; q < 4;  q++) async16(Bgn + (size_t)q * 32 * ldb, BsW + q * 2048);
        }
        const unsigned short* Ab = As + sel * ABUF;
        const unsigned short* Bb = Bs + sel * BBUF;
        #pragma unroll
        for (int kh = 0; kh < 2; kh++) {
            const int off = off0 ^ (kh * 32);
            short8 a[TI], b[4];
            #pragma unroll
            for (int i = 0; i < TI; i++)
                a[i] = *(const short8*)(Ab + (wr + i*16 + fr) * 64 + off);
            #pragma unroll
            for (int j = 0; j < 4;  j++)
                b[j] = *(const short8*)(Bb + (wc + j*16 + fr) * 64 + off);
            #pragma unroll
            for (int i = 0; i < TI; i++)
                #pragma unroll
                for (int j = 0; j < 4; j++)
                    acc[i][j] = __builtin_amdgcn_mfma_f32_16x16x32_bf16(
                        a[i], b[j], acc[i][j], 0, 0, 0);
        }
        asm volatile("s_waitcnt vmcnt(0)" ::: "memory");
        __syncthreads();
        sel ^= 1;
    }
}

// ---------------------------------------------------------------------------
// fp8 core, double-buffered, BM=32*TI x 128 tile: C = A8 @ B8^T, both
// row-major [*][NN] bytes, BK=128.
// ---------------------------------------------------------------------------
template<int TI>
__device__ __forceinline__ void gemm8_db(
    const unsigned char* __restrict__ Amat,
    const unsigned char* __restrict__ Bmat,
    int kb, int klen, int row0, int col0,
    unsigned char* As, unsigned char* Bs,
    f32x4 (&acc)[TI][4])
{
    const int tid  = threadIdx.x;
    const int lane = tid & 63;
    const int wave = tid >> 6;
    const int srow = lane >> 3;
    const int sblk = lane & 7;
    const int ABUF = TI * 32 * 128;
    const int BBUF = 128 * 128;

    const unsigned char* Ag = Amat + (size_t)(row0 + wave*8 + srow) * NN
                                   + ((sblk ^ srow) * 16) + kb;
    const unsigned char* Bg = Bmat + (size_t)(col0 + wave*8 + srow) * NN
                                   + ((sblk ^ srow) * 16) + kb;

    const int fr = lane & 15;
    const int fq = lane >> 4;
    const int wr = (wave >> 1) * (TI * 16);
    const int wc = (wave & 1) * 64;
    int offk[4];
    #pragma unroll
    for (int kq = 0; kq < 4; kq++)
        offk[kq] = (((kq*2 + (fq >> 1)) ^ (fr & 7)) << 4) + ((fq & 1) << 3);

    {
        unsigned char* AsW = As + wave * 1024;
        unsigned char* BsW = Bs + wave * 1024;
        #pragma unroll
        for (int q = 0; q < TI; q++) async16(Ag + (size_t)q * 32 * NN, AsW + q * 4096);
        #pragma unroll
        for (int q = 0; q < 4;  q++) async16(Bg + (size_t)q * 32 * NN, BsW + q * 4096);
    }
    asm volatile("s_waitcnt vmcnt(0)" ::: "memory");
    __syncthreads();

    const int nk = klen >> 7;
    int sel = 0;
    for (int it = 0; it < nk; ++it) {
        if (it + 1 < nk) {
            const unsigned char* Agn = Ag + (size_t)(it + 1) * 128;
            const unsigned char* Bgn = Bg + (size_t)(it + 1) * 128;
            unsigned char* AsW = As + (sel ^ 1) * ABUF + wave * 1024;
            unsigned char* BsW = Bs + (sel ^ 1) * BBUF + wave * 1024;
            #pragma unroll
            for (int q = 0; q < TI; q++) async16(Agn + (size_t)q * 32 * NN, AsW + q * 4096);
            #pragma unroll
            for (int q = 0; q < 4;  q++) async16(Bgn + (size_t)q * 32 * NN, BsW + q * 4096);
        }
        const unsigned char* Ab = As + sel * ABUF;
        const unsigned char* Bb = Bs + sel * BBUF;
        #pragma unroll
        for (int kq = 0; kq < 4; kq++) {
            long a[TI], b[4];
            #pragma unroll
            for (int i = 0; i < TI; i++) a[i] = *(const long*)(Ab + (wr + i*16 + fr) * 128 + offk[kq]);
            #pragma unroll
            for (int j = 0; j < 4;  j++) b[j] = *(const long*)(Bb + (wc + j*16 + fr) * 128 + offk[kq]);
            #pragma unroll
            for (int i = 0; i < TI; i++)
                #pragma unroll
                for (int j = 0; j < 4; j++)
                    acc[i][j] = __builtin_amdgcn_mfma_f32_16x16x32_fp8_fp8(
                        a[i], b[j], acc[i][j], 0, 0, 0);
        }
        asm volatile("s_waitcnt vmcnt(0)" ::: "memory");
        __syncthreads();
        sel ^= 1;
    }
}

// ---------------- prep (once per launch) ----------------

__global__ __launch_bounds__(256) void k_prep_a(const float* __restrict__ A,
                                                unsigned char* __restrict__ A8) {
    size_t i = (size_t)blockIdx.x * blockDim.x + threadIdx.x;
    size_t stride = (size_t)gridDim.x * blockDim.x;
    size_t total = (size_t)NN * NN / 4;
    for (; i < total; i += stride) {
        float4 v = ((const float4*)A)[i];
        unsigned pk = (unsigned)f2e4m3(v.x * ASCALE)
                    | ((unsigned)f2e4m3(v.y * ASCALE) << 8)
                    | ((unsigned)f2e4m3(v.z * ASCALE) << 16)
                    | ((unsigned)f2e4m3(v.w * ASCALE) << 24);
        ((unsigned*)A8)[i] = pk;
    }
}

__global__ __launch_bounds__(256) void k_prep_w(
    const float* __restrict__ Wgh, const float* __restrict__ Wgc,
    const float* __restrict__ rk,  const float* __restrict__ kern,
    const float* __restrict__ lb,
    const float* __restrict__ Whc, const float* __restrict__ Whp,
    const float* __restrict__ Wcc, const float* __restrict__ Wcp,
    unsigned short* __restrict__ WzTb, unsigned short* __restrict__ WgT,
    unsigned short* __restrict__ WU, float* __restrict__ biasg)
{
    int i = blockIdx.x * blockDim.x + threadIdx.x;
    int stride = gridDim.x * blockDim.x;
    for (int x = i; x < 1024 * KG; x += stride) {
        int col = x / KG, k = x % KG;
        int oc = (col & 3) * 256 + (col >> 2);
        float val = 0.f;
        if (k < 256) val = rk[k * 1024 + oc];
        else if (k < 272) val = kern[(k - 256) * 1024 + oc];
        WzTb[x] = f2bf(val);
    }
    for (int x = i; x < 512 * 256; x += stride) {
        int col = x >> 8, k = x & 255;
        float val = (col < 256) ? Wgh[k * 256 + col] : Wgc[k * 256 + (col - 256)];
        WgT[x] = f2bf(val);
    }
    for (int x = i; x < 512 * 512; x += stride) {
        int col = x >> 9, k = x & 511;
        float val;
        if (col < 256)
            val = (k < 256) ? Whc[k * 256 + col] : Whp[(k - 256) * 256 + col];
        else {
            int c2 = col - 256;
            val = (k < 256) ? Wcc[k * 256 + c2] : Wcp[(k - 256) * 256 + c2];
        }
        WU[x] = f2bf(val);
    }
    for (int x = i; x < 1024; x += stride)
        biasg[x] = lb[(x & 3) * 256 + (x >> 2)];
}

__global__ __launch_bounds__(256) void k_prep_s(const float* __restrict__ inputs,
                                                unsigned short* __restrict__ HCb,
                                                unsigned char* __restrict__ hwT8,
                                                float* __restrict__ Cstate)
{
    int i = blockIdx.x * blockDim.x + threadIdx.x;
    int stride = gridDim.x * blockDim.x;
    for (int x = i; x < NN * KG; x += stride) {
        int n = x / KG, col = x % KG;
        unsigned short v = 0;
        if (col >= 256 && col < 272)
            v = f2bf(inputs[(size_t)n * TD + (col - 256)]);
        HCb[x] = v;
    }
    for (int x = i; x < 512 * NN / 4; x += stride) ((unsigned*)hwT8)[x] = 0;
    for (int x = i; x < NN * HH; x += stride) Cstate[x] = 0.f;
}

// ---------------- per-step kernels ----------------

// kA: bid<128 -> graph states: tanh(A8 @ hwT8^T * AINV2 + bg) -> LHS3 graph cols
//              (128x128 tiles, XCD-grouped so each XCD reuses 4 A8 row-tiles)
//     bid>=128 -> gates GEMM + LSTM elementwise -> LHS3 cur cols
// LHS3: [h_cur(0-255) | h_graph(256-511) | c_cur(512-767) | c_graph(768-1023)]
__global__ __launch_bounds__(256) void k_a(
    const unsigned char* __restrict__ A8,     // [4096][4096] (x4096 scale)
    const unsigned char* __restrict__ hwT8,   // [512][4096]: HWh 0-255, HWc 256-511 (x64)
    const float* __restrict__ bgh, const float* __restrict__ bgc,
    const unsigned short* __restrict__ HCb,   // [4096][KG]
    const unsigned short* __restrict__ WzTb,  // [1024][KG]
    const float* __restrict__ biasg,
    const float* __restrict__ Cstate,
    unsigned short* __restrict__ LHS3)        // [4096][1024]
{
    __shared__ __align__(16) unsigned char smem[65536];
    const int bid = blockIdx.x;
    const int tid = threadIdx.x;
    const int lane = tid & 63;
    const int wave = tid >> 6;
    const int fr = lane & 15;
    const int rq = (lane >> 4) * 4;

    if (bid < 128) {
        // XCD-grouped mapping: xcd x owns row-tiles x*4..x*4+3, all 4 col-tiles
        const int x  = bid & 7;
        const int kk = bid >> 3;
        const int row0 = (x * 4 + (kk >> 2)) * 128;
        const int col0 = (kk & 3) * 128;
        f32x4 acc[4][4] = {};
        gemm8_db<4>(A8, hwT8, 0, NN, row0, col0, smem, smem + 32768, acc);
        const int wr = (wave >> 1) * 64;
        const int wc = (wave & 1) * 64;
        #pragma unroll
        for (int i = 0; i < 4; i++)
            #pragma unroll
            for (int j = 0; j < 4; j++) {
                int c = col0 + wc + j * 16 + fr;          // HW col 0..511
                float bias = (c < 256) ? bgh[c] : bgc[c - 256];
                int dst = (c < 256) ? (c + 256) : (c + 512);
                int rbase = row0 + wr + i * 16 + rq;
                #pragma unroll
                for (int r = 0; r < 4; r++)
                    LHS3[(size_t)(rbase + r) * 1024 + dst] =
                        f2bf(tanhf_(acc[i][j][r] * AINV2 + bias));
            }
    } else {
        // ---- gates: z = [h|x] @ Wz + b -> LSTM elementwise ----
        const int b2 = bid - 128;
        f32x4 acc[4][4] = {};
        const int row0 = (b2 >> 3) * 128;
        const int col0 = (b2 & 7) * 128;
        gemm_core_db<4>(HCb, KG, WzTb, KG, KG, row0, col0,
                        (unsigned short*)smem, (unsigned short*)(smem + 32768), acc);
        const int wr = (wave >> 1) * 64, wc = (wave & 1) * 64;
        const int g = lane & 3;
        #pragma unroll
        for (int i = 0; i < 4; i++)
            #pragma unroll
            for (int j = 0; j < 4; j++) {
                int c = col0 + wc + j * 16 + fr;
                int rbase = row0 + wr + i * 16 + rq;
                float bias = biasg[c];
                int h = c >> 2;
                #pragma unroll
                for (int r = 0; r < 4; r++) {
                    float v = acc[i][j][r] + bias;
                    float z_i = __shfl(v, (lane & ~3) | 0, 64);
                    float z_f = __shfl(v, (lane & ~3) | 1, 64);
                    float z_g = __shfl(v, (lane & ~3) | 2, 64);
                    float z_o = __shfl(v, (lane & ~3) | 3, 64);
                    if (g < 2) {
                        int n = rbase + r;
                        float cp = Cstate[n * HH + h];
                        float ccur = sigmoidf_(z_f) * cp + sigmoidf_(z_i) * tanhf_(z_g);
                        if (g == 0) {
                            float hcur = sigmoidf_(z_o) * tanhf_(ccur);
                            LHS3[(size_t)n * 1024 + h] = f2bf(hcur);
                        } else {
                            LHS3[(size_t)n * 1024 + 512 + h] = f2bf(ccur);
                        }
                    }
                }
            }
    }
}

// k_uf (fused): per block: 32 rows x one U-half (256 cols).
//  stage1: U = sigmoid(LHS3[:,half*512:+512] @ WU[:,half*256:+256] + b)  K=512
//  epilogue: U -> LDS (swizzled bf16), HCb/Cstate, out_pred partials (half 0)
//  stage2: HW = U @ Wg^T (K=256, block-local) -> x64 -> fp8 transposed hwT8
//  wave layout 1x4: wave w owns cols w*64..w*64+63. BM=32 (TI=2).
__global__ __launch_bounds__(256) void k_uf(
    const unsigned short* __restrict__ LHS3,  // [4096][1024]
    const unsigned short* __restrict__ WU,    // [512][512]
    const unsigned short* __restrict__ WgT,   // [512][256]
    const float* __restrict__ b_h, const float* __restrict__ b_c,
    const float* __restrict__ W_out, const float* __restrict__ b_out,
    float* __restrict__ Cstate,
    unsigned short* __restrict__ HCb,
    unsigned char* __restrict__ hwT8,         // [512][4096]
    float* __restrict__ d_out,
    const float* __restrict__ inputs, int t)
{
    // LDS: stage1 As 2x(32x64) @0 (8KB), Bs 2x(256x64) @8K (64KB)
    //      stage2 alias: Us (32x256) @0 (16KB), B2s (256x64) @16K (32KB)
    //      outred @72K (1KB)
    __shared__ __align__(16) unsigned char smem[74752];
    unsigned short* As  = (unsigned short*)smem;
    unsigned short* Bs  = (unsigned short*)(smem + 8192);
    unsigned short* Us  = (unsigned short*)smem;
    unsigned short* B2s = (unsigned short*)(smem + 16384);
    float* outred = (float*)(smem + 73728);

    const int bid  = blockIdx.x;
    const int tid  = threadIdx.x;
    const int lane = tid & 63;
    const int wave = tid >> 6;
    const int fr   = lane & 15;
    const int fq   = lane >> 4;
    const int rq   = fq * 4;
    const int srow = lane >> 3;
    const int sblk = lane & 7;

    const int half = bid & 1;
    const int row0 = (bid >> 1) * 32;
    const int wc   = wave * 64;
    const int off0 = ((fq ^ (fr & 7)) * 8);
    const int ABUF = 2048, BBUF = 16384;

    // ---- stage 1: K=512 ----
    const unsigned short* Ag = LHS3 + half*512
        + (size_t)(row0 + wave*8 + srow) * 1024 + ((sblk ^ srow) * 8);
    const unsigned short* Bg = WU
        + (size_t)(half*256 + wave*64 + srow) * 512 + ((sblk ^ srow) * 8);

    {
        async16(Ag, As + wave*512);
        #pragma unroll
        for (int q = 0; q < 8; q++)
            async16(Bg + (size_t)q*8*512, Bs + wave*4096 + q*512);
    }
    asm volatile("s_waitcnt vmcnt(0)" ::: "memory");
    __syncthreads();

    f32x4 acc[2][4] = {};
    int sel = 0;
    for (int it = 0; it < 8; ++it) {
        if (it + 1 < 8) {
            const unsigned short* Agn = Ag + (it + 1) * 64;
            const unsigned short* Bgn = Bg + (it + 1) * 64;
            async16(Agn, As + (sel^1)*ABUF + wave*512);
            #pragma unroll
            for (int q = 0; q < 8; q++)
                async16(Bgn + (size_t)q*8*512, Bs + (sel^1)*BBUF + wave*4096 + q*512);
        }
        const unsigned short* Ab = As + sel*ABUF;
        const unsigned short* Bb = Bs + sel*BBUF;
        #pragma unroll
        for (int kh = 0; kh < 2; kh++) {
            const int off = off0 ^ (kh * 32);
            short8 a[2], b[4];
            #pragma unroll
            for (int i = 0; i < 2; i++)
                a[i] = *(const short8*)(Ab + (i*16 + fr) * 64 + off);
            #pragma unroll
            for (int j = 0; j < 4; j++)
                b[j] = *(const short8*)(Bb + (wc + j*16 + fr) * 64 + off);
            #pragma unroll
            for (int i = 0; i < 2; i++)
                #pragma unroll
                for (int j = 0; j < 4; j++)
                    acc[i][j] = __builtin_amdgcn_mfma_f32_16x16x32_bf16(
                        a[i], b[j], acc[i][j], 0, 0, 0);
        }
        asm volatile("s_waitcnt vmcnt(0)" ::: "memory");
        __syncthreads();
        sel ^= 1;
    }

    // ---- stage-1 epilogue: sigmoid, write Us(swizzled)/HCb/Cstate, out partials
    const float* bias = half ? b_c : b_h;
    float pr0[8], pr1[8];
    #pragma unroll
    for (int m = 0; m < 8; m++) { pr0[m] = 0.f; pr1[m] = 0.f; }
    #pragma unroll
    for (int i = 0; i < 2; i++)
        #pragma unroll
        for (int j = 0; j < 4; j++) {
            const int cl = wc + j*16 + fr;                // 0..255 within half
            const float bv = bias[cl];
            const int blk = j*2 + (fr >> 3);
            float w0 = 0.f, w1 = 0.f;
            if (half == 0) { w0 = W_out[cl*2 + 0]; w1 = W_out[cl*2 + 1]; }
            #pragma unroll
            for (int r = 0; r < 4; r++) {
                const int rl = i*16 + rq + r;             // 0..31
                const int n = row0 + rl;
                float v = sigmoidf_(acc[i][j][r] + bv);
                unsigned short vb = f2bf(v);
                Us[rl*256 + wave*64 + ((blk ^ (rl & 7)) * 8) + (fr & 7)] = vb;
                if (half == 0) {
                    HCb[(size_t)n * KG + cl] = vb;
                    pr0[i*4 + r] += v * w0;
                    pr1[i*4 + r] += v * w1;
                } else {
                    Cstate[(size_t)n * HH + cl] = v;
                }
            }
        }
    if (half == 0) {
        #pragma unroll
        for (int m = 0; m < 8; m++) {
            #pragma unroll
            for (int s = 1; s < 16; s <<= 1) {
                pr0[m] += __shfl_xor(pr0[m], s, 64);
                pr1[m] += __shfl_xor(pr1[m], s, 64);
            }
        }
        if (fr == 0) {
            #pragma unroll
            for (int i = 0; i < 2; i++)
                #pragma unroll
                for (int r = 0; r < 4; r++) {
                    int rl = i*16 + rq + r;
                    outred[(wave*32 + rl)*2 + 0] = pr0[i*4 + r];
                    outred[(wave*32 + rl)*2 + 1] = pr1[i*4 + r];
                }
        }
    }
    __syncthreads();   // Us + outred visible
    if (half == 0 && tid < 64) {
        int rl = tid >> 1, p = tid & 1;
        float s = b_out[p];
        #pragma unroll
        for (int w = 0; w < 4; w++) s += outred[(w*32 + rl)*2 + p];
        d_out[(size_t)(row0 + rl) * TP + t * PP + p] = s;
    }

    // ---- stage 2: HW = U @ Wg^T, K=256 (block-local), 4 chunks, single-buffer
    f32x4 acc2[2][4] = {};
    const unsigned short* Bg2 = WgT
        + (size_t)(half*256 + wave*64 + srow) * 256 + ((sblk ^ srow) * 8);
    for (int kc2 = 0; kc2 < 4; ++kc2) {
        __syncthreads();           // previous chunk's reads done
        #pragma unroll
        for (int q = 0; q < 8; q++)
            async16(Bg2 + (size_t)q*8*256 + kc2*64, B2s + wave*4096 + q*512);
        asm volatile("s_waitcnt vmcnt(0)" ::: "memory");
        __syncthreads();
        #pragma unroll
        for (int kh = 0; kh < 2; kh++) {
            const int off = off0 ^ (kh * 32);
            short8 a[2], b[4];
            #pragma unroll
            for (int i = 0; i < 2; i++)
                a[i] = *(const short8*)(Us + (i*16 + fr) * 256 + kc2*64 + off);
            #pragma unroll
            for (int j = 0; j < 4; j++)
                b[j] = *(const short8*)(B2s + (wc + j*16 + fr) * 64 + off);
            #pragma unroll
            for (int i = 0; i < 2; i++)
                #pragma unroll
                for (int j = 0; j < 4; j++)
                    acc2[i][j] = __builtin_amdgcn_mfma_f32_16x16x32_bf16(
                        a[i], b[j], acc2[i][j], 0, 0, 0);
        }
    }
    // hwT8[cg][n] fp8 transposed store
    #pragma unroll
    for (int i = 0; i < 2; i++)
        #pragma unroll
        for (int j = 0; j < 4; j++) {
            int cg = half*256 + wc + j*16 + fr;
            int rbase = row0 + i*16 + rq;
            unsigned pk = (unsigned)f2e4m3(acc2[i][j][0] * HWSCALE)
                        | ((unsigned)f2e4m3(acc2[i][j][1] * HWSCALE) << 8)
                        | ((unsigned)f2e4m3(acc2[i][j][2] * HWSCALE) << 16)
                        | ((unsigned)f2e4m3(acc2[i][j][3] * HWSCALE) << 24);
            *(unsigned*)(hwT8 + (size_t)cg * NN + rbase) = pk;
        }

    // x_{t+1} prefetch into HCb
    int gid = bid * 256 + tid;                            // 0..65535
    if (t + 1 < TT) {
        int n = gid >> 4, d = gid & 15;
        HCb[(size_t)n * KG + 256 + d] = f2bf(inputs[(size_t)n * TD + (t + 1) * DD + d]);
    }
}

extern "C" void kernel_launch(void* const* d_in, const int* in_sizes, int n_in,
                              void* d_out_v, int out_size, void* d_ws, size_t ws_size,
                              hipStream_t stream)
{
    const float* inputs = (const float*)d_in[0];
    const float* A      = (const float*)d_in[1];
    const float* kern   = (const float*)d_in[2];
    const float* rk     = (const float*)d_in[3];
    const float* lb     = (const float*)d_in[4];
    const float* Wgh    = (const float*)d_in[5];
    const float* bgh    = (const float*)d_in[6];
    const float* Wgc    = (const float*)d_in[7];
    const float* bgc    = (const float*)d_in[8];
    const float* Whc    = (const float*)d_in[9];
    const float* Whp    = (const float*)d_in[10];
    const float* bh     = (const float*)d_in[11];
    const float* Wcc    = (const float*)d_in[12];
    const float* Wcp    = (const float*)d_in[13];
    const float* bc     = (const float*)d_in[14];
    const float* Wout   = (const float*)d_in[15];
    const float* bout   = (const float*)d_in[16];
    float* d_out = (float*)d_out_v;

    char* ws = (char*)d_ws;
    size_t off = 0;
    auto alloc = [&](size_t bytes) {
        char* p = ws + off;
        off += (bytes + 255) & ~(size_t)255;
        return p;
    };
    unsigned char*  A8    = (unsigned char*) alloc((size_t)NN * NN);           // 16 MB
    unsigned char*  hwT8  = (unsigned char*) alloc((size_t)512 * NN);          // 2 MB
    unsigned short* HCb   = (unsigned short*)alloc((size_t)NN * KG * 2);       // 2.5 MB
    unsigned short* WzTb  = (unsigned short*)alloc((size_t)1024 * KG * 2);
    unsigned short* WgT   = (unsigned short*)alloc((size_t)512 * 256 * 2);
    unsigned short* WU    = (unsigned short*)alloc((size_t)512 * 512 * 2);
    float*          biasg = (float*)         alloc(1024 * 4);
    unsigned short* LHS3  = (unsigned short*)alloc((size_t)NN * 1024 * 2);     // 8 MB
    float*          Cst   = (float*)         alloc((size_t)NN * HH * 4);       // 4 MB
    (void)in_sizes; (void)n_in; (void)out_size; (void)ws_size;

    k_prep_a<<<2048, 256, 0, stream>>>(A, A8);
    k_prep_w<<<256, 256, 0, stream>>>(Wgh, Wgc, rk, kern, lb,
                                      Whc, Whp, Wcc, Wcp, WzTb, WgT, WU, biasg);
    k_prep_s<<<512, 256, 0, stream>>>(inputs, HCb, hwT8, Cst);

    for (int t = 0; t < TT; t++) {
        k_a<<<384, 256, 0, stream>>>(A8, hwT8, bgh, bgc,
                                     HCb, WzTb, biasg, Cst, LHS3);
        k_uf<<<256, 256, 0, stream>>>(LHS3, WU, WgT, bh, bc, Wout, bout,
                                      Cst, HCb, hwT8, d_out, inputs, t);
    }
}

// Round 4
// 21257.472 us; speedup vs baseline: 1.4141x; 1.0507x over previous
//
#include <hip/hip_runtime.h>

using short8 = __attribute__((ext_vector_type(8))) short;
using f32x4  = __attribute__((ext_vector_type(4))) float;

#define NN 4096
#define TT 365
#define DD 16
#define HH 256
#define PP 2
#define TD (TT*DD)      // 5840
#define TP (TT*PP)      // 730
#define KG 320          // gates K: [h(256) | x(16) | pad(48)]
#define ASCALE 4096.0f
#define HWSCALE 64.0f
#define AINV2 (1.0f/(4096.0f*64.0f))   // A8 scale * hwT8 scale

__device__ __forceinline__ unsigned short f2bf(float f) {
    union { float f; unsigned u; } v; v.f = f;
    unsigned r = v.u + 0x7FFFu + ((v.u >> 16) & 1u);   // RNE
    return (unsigned short)(r >> 16);
}
// float -> OCP e4m3fn, RNE, saturating at 448
__device__ __forceinline__ unsigned char f2e4m3(float f) {
    union { float f; unsigned u; } v; v.f = f;
    unsigned s = (v.u >> 24) & 0x80u;
    unsigned au = v.u & 0x7fffffffu;
    if (au >= 0x43E00000u) return (unsigned char)(s | 0x7E);   // >=448 -> 448
    if (au < 0x3C800000u) {                                    // <2^-6: subnormal
        int m = __float2int_rn(__uint_as_float(au) * 512.0f);  // 0..8
        return (unsigned char)(s | (unsigned)m);
    }
    unsigned r = au + 0x7FFFFu + ((au >> 20) & 1u);            // RNE to 3 mantissa bits
    return (unsigned char)(s | ((r >> 20) - 0x3C0u));
}
__device__ __forceinline__ float sigmoidf_(float x) {
    return 1.0f / (1.0f + __expf(-x));
}
__device__ __forceinline__ float tanhf_(float x) {
    float t = __expf(2.0f * x);
    return (t - 1.0f) / (t + 1.0f);
}
__device__ __forceinline__ void async16(const void* g, void* l) {
    __builtin_amdgcn_global_load_lds(
        (const __attribute__((address_space(1))) void*)g,
        (__attribute__((address_space(3))) void*)l, 16, 0, 0);
}

// ---------------------------------------------------------------------------
// bf16 core, double-buffered: 256 thr = 4 waves 2x2. BN=128, BK=64, BM=32*TI.
// C = Amat(row-major,lda) @ Bt^T (Bt[col][k],ldb). 16B-block XOR swizzle.
// C frag: col = lane&15, row = (lane>>4)*4 + reg.
// ---------------------------------------------------------------------------
template<int TI>
__device__ __forceinline__ void gemm_core_db(
    const unsigned short* __restrict__ Amat, int lda,
    const unsigned short* __restrict__ Bt,  int ldb,
    int k_len, int row0, int col0,
    unsigned short* As, unsigned short* Bs,
    f32x4 (&acc)[TI][4])
{
    const int tid  = threadIdx.x;
    const int lane = tid & 63;
    const int wave = tid >> 6;
    const int srow = lane >> 3;
    const int sblk = lane & 7;
    const int ABUF = TI * 32 * 64;     // shorts per A buffer
    const int BBUF = 128 * 64;         // shorts per B buffer

    const unsigned short* Ag = Amat + (size_t)(row0 + wave*8 + srow) * lda
                                    + ((sblk ^ srow) * 8);
    const unsigned short* Bg = Bt   + (size_t)(col0 + wave*8 + srow) * ldb
                                    + ((sblk ^ srow) * 8);

    const int fr = lane & 15;
    const int fq = lane >> 4;
    const int wr = (wave >> 1) * (TI * 16);
    const int wc = (wave & 1) * 64;
    const int off0 = ((fq ^ (fr & 7)) * 8);

    {
        unsigned short* AsW = As + wave * 512;
        unsigned short* BsW = Bs + wave * 512;
        #pragma unroll
        for (int q = 0; q < TI; q++) async16(Ag + (size_t)q * 32 * lda, AsW + q * 2048);
        #pragma unroll
        for (int q = 0; q < 4;  q++) async16(Bg + (size_t)q * 32 * ldb, BsW + q * 2048);
    }
    asm volatile("s_waitcnt vmcnt(0)" ::: "memory");
    __syncthreads();

    const int nk = k_len >> 6;
    int sel = 0;
    for (int it = 0; it < nk; ++it) {
        if (it + 1 < nk) {
            const unsigned short* Agn = Ag + (it + 1) * 64;
            const unsigned short* Bgn = Bg + (it + 1) * 64;
            unsigned short* AsW = As + (sel ^ 1) * ABUF + wave * 512;
            unsigned short* BsW = Bs + (sel ^ 1) * BBUF + wave * 512;
            #pragma unroll
            for (int q = 0; q < TI; q++) async16(Agn + (size_t)q * 32 * lda, AsW + q * 2048);
            #pragma unroll
            for (int q = 0; q < 4;  q++) async16(Bgn + (size_t)q * 32 * ldb, BsW + q * 2048);
        }
        const unsigned short* Ab = As + sel * ABUF;
        const unsigned short* Bb = Bs + sel * BBUF;
        #pragma unroll
        for (int kh = 0; kh < 2; kh++) {
            const int off = off0 ^ (kh * 32);
            short8 a[TI], b[4];
            #pragma unroll
            for (int i = 0; i < TI; i++)
                a[i] = *(const short8*)(Ab + (wr + i*16 + fr) * 64 + off);
            #pragma unroll
            for (int j = 0; j < 4;  j++)
                b[j] = *(const short8*)(Bb + (wc + j*16 + fr) * 64 + off);
            #pragma unroll
            for (int i = 0; i < TI; i++)
                #pragma unroll
                for (int j = 0; j < 4; j++)
                    acc[i][j] = __builtin_amdgcn_mfma_f32_16x16x32_bf16(
                        a[i], b[j], acc[i][j], 0, 0, 0);
        }
        asm volatile("s_waitcnt vmcnt(0)" ::: "memory");
        __syncthreads();
        sel ^= 1;
    }
}

// ---------------------------------------------------------------------------
// fp8 core, double-buffered, BM=32*TI x 128 tile: C = A8 @ B8^T, both
// row-major [*][NN] bytes, BK=128.
// ---------------------------------------------------------------------------
template<int TI>
__device__ __forceinline__ void gemm8_db(
    const unsigned char* __restrict__ Amat,
    const unsigned char* __restrict__ Bmat,
    int kb, int klen, int row0, int col0,
    unsigned char* As, unsigned char* Bs,
    f32x4 (&acc)[TI][4])
{
    const int tid  = threadIdx.x;
    const int lane = tid & 63;
    const int wave = tid >> 6;
    const int srow = lane >> 3;
    const int sblk = lane & 7;
    const int ABUF = TI * 32 * 128;
    const int BBUF = 128 * 128;

    const unsigned char* Ag = Amat + (size_t)(row0 + wave*8 + srow) * NN
                                   + ((sblk ^ srow) * 16) + kb;
    const unsigned char* Bg = Bmat + (size_t)(col0 + wave*8 + srow) * NN
                                   + ((sblk ^ srow) * 16) + kb;

    const int fr = lane & 15;
    const int fq = lane >> 4;
    const int wr = (wave >> 1) * (TI * 16);
    const int wc = (wave & 1) * 64;
    int offk[4];
    #pragma unroll
    for (int kq = 0; kq < 4; kq++)
        offk[kq] = (((kq*2 + (fq >> 1)) ^ (fr & 7)) << 4) + ((fq & 1) << 3);

    {
        unsigned char* AsW = As + wave * 1024;
        unsigned char* BsW = Bs + wave * 1024;
        #pragma unroll
        for (int q = 0; q < TI; q++) async16(Ag + (size_t)q * 32 * NN, AsW + q * 4096);
        #pragma unroll
        for (int q = 0; q < 4;  q++) async16(Bg + (size_t)q * 32 * NN, BsW + q * 4096);
    }
    asm volatile("s_waitcnt vmcnt(0)" ::: "memory");
    __syncthreads();

    const int nk = klen >> 7;
    int sel = 0;
    for (int it = 0; it < nk; ++it) {
        if (it + 1 < nk) {
            const unsigned char* Agn = Ag + (size_t)(it + 1) * 128;
            const unsigned char* Bgn = Bg + (size_t)(it + 1) * 128;
            unsigned char* AsW = As + (sel ^ 1) * ABUF + wave * 1024;
            unsigned char* BsW = Bs + (sel ^ 1) * BBUF + wave * 1024;
            #pragma unroll
            for (int q = 0; q < TI; q++) async16(Agn + (size_t)q * 32 * NN, AsW + q * 4096);
            #pragma unroll
            for (int q = 0; q < 4;  q++) async16(Bgn + (size_t)q * 32 * NN, BsW + q * 4096);
        }
        const unsigned char* Ab = As + sel * ABUF;
        const unsigned char* Bb = Bs + sel * BBUF;
        #pragma unroll
        for (int kq = 0; kq < 4; kq++) {
            long a[TI], b[4];
            #pragma unroll
            for (int i = 0; i < TI; i++) a[i] = *(const long*)(Ab + (wr + i*16 + fr) * 128 + offk[kq]);
            #pragma unroll
            for (int j = 0; j < 4;  j++) b[j] = *(const long*)(Bb + (wc + j*16 + fr) * 128 + offk[kq]);
            #pragma unroll
            for (int i = 0; i < TI; i++)
                #pragma unroll
                for (int j = 0; j < 4; j++)
                    acc[i][j] = __builtin_amdgcn_mfma_f32_16x16x32_fp8_fp8(
                        a[i], b[j], acc[i][j], 0, 0, 0);
        }
        asm volatile("s_waitcnt vmcnt(0)" ::: "memory");
        __syncthreads();
        sel ^= 1;
    }
}

// ---------------- prep (once per launch) ----------------

__global__ __launch_bounds__(256) void k_prep_a(const float* __restrict__ A,
                                                unsigned char* __restrict__ A8) {
    size_t i = (size_t)blockIdx.x * blockDim.x + threadIdx.x;
    size_t stride = (size_t)gridDim.x * blockDim.x;
    size_t total = (size_t)NN * NN / 4;
    for (; i < total; i += stride) {
        float4 v = ((const float4*)A)[i];
        unsigned pk = (unsigned)f2e4m3(v.x * ASCALE)
                    | ((unsigned)f2e4m3(v.y * ASCALE) << 8)
                    | ((unsigned)f2e4m3(v.z * ASCALE) << 16)
                    | ((unsigned)f2e4m3(v.w * ASCALE) << 24);
        ((unsigned*)A8)[i] = pk;
    }
}

__global__ __launch_bounds__(256) void k_prep_w(
    const float* __restrict__ Wgh, const float* __restrict__ Wgc,
    const float* __restrict__ rk,  const float* __restrict__ kern,
    const float* __restrict__ lb,
    const float* __restrict__ Whc, const float* __restrict__ Whp,
    const float* __restrict__ Wcc, const float* __restrict__ Wcp,
    unsigned short* __restrict__ WzTb, unsigned short* __restrict__ WgT,
    unsigned short* __restrict__ WU, float* __restrict__ biasg)
{
    int i = blockIdx.x * blockDim.x + threadIdx.x;
    int stride = gridDim.x * blockDim.x;
    for (int x = i; x < 1024 * KG; x += stride) {
        int col = x / KG, k = x % KG;
        int oc = (col & 3) * 256 + (col >> 2);
        float val = 0.f;
        if (k < 256) val = rk[k * 1024 + oc];
        else if (k < 272) val = kern[(k - 256) * 1024 + oc];
        WzTb[x] = f2bf(val);
    }
    for (int x = i; x < 512 * 256; x += stride) {
        int col = x >> 8, k = x & 255;
        float val = (col < 256) ? Wgh[k * 256 + col] : Wgc[k * 256 + (col - 256)];
        WgT[x] = f2bf(val);
    }
    for (int x = i; x < 512 * 512; x += stride) {
        int col = x >> 9, k = x & 511;
        float val;
        if (col < 256)
            val = (k < 256) ? Whc[k * 256 + col] : Whp[(k - 256) * 256 + col];
        else {
            int c2 = col - 256;
            val = (k < 256) ? Wcc[k * 256 + c2] : Wcp[(k - 256) * 256 + c2];
        }
        WU[x] = f2bf(val);
    }
    for (int x = i; x < 1024; x += stride)
        biasg[x] = lb[(x & 3) * 256 + (x >> 2)];
}

__global__ __launch_bounds__(256) void k_prep_s(const float* __restrict__ inputs,
                                                unsigned short* __restrict__ HCb,
                                                unsigned char* __restrict__ hwT8,
                                                float* __restrict__ Cstate)
{
    int i = blockIdx.x * blockDim.x + threadIdx.x;
    int stride = gridDim.x * blockDim.x;
    for (int x = i; x < NN * KG; x += stride) {
        int n = x / KG, col = x % KG;
        unsigned short v = 0;
        if (col >= 256 && col < 272)
            v = f2bf(inputs[(size_t)n * TD + (col - 256)]);
        HCb[x] = v;
    }
    for (int x = i; x < 512 * NN / 4; x += stride) ((unsigned*)hwT8)[x] = 0;
    for (int x = i; x < NN * HH; x += stride) Cstate[x] = 0.f;
}

// ---------------- per-step kernels ----------------

// kA: 512 blocks, 2/CU.
//  bid<256: fp8 partials, K-split x2. XCD-aware: bid%8 -> XCD; XCDs 0-3 do
//   K-half 0, XCDs 4-7 K-half 1. Each XCD: 8 row-tiles x 4 col-tiles ->
//   L2 working set = A-slice 2MB + hwT8-half 1MB = 3MB < 4MB.
//   Output: raw f32 partial to P0/P1 [4096][512].
//  bid>=256: gates GEMM + LSTM elementwise -> LHS2 [4096][512] = [h_cur|c_cur]
__global__ __launch_bounds__(256, 2) void k_a(
    const unsigned char* __restrict__ A8,     // [4096][4096] (x4096 scale)
    const unsigned char* __restrict__ hwT8,   // [512][4096]: HWh 0-255, HWc 256-511 (x64)
    const unsigned short* __restrict__ HCb,   // [4096][KG]
    const unsigned short* __restrict__ WzTb,  // [1024][KG]
    const float* __restrict__ biasg,
    const float* __restrict__ Cstate,
    unsigned short* __restrict__ LHS2,        // [4096][512]
    float* __restrict__ P0, float* __restrict__ P1)
{
    __shared__ __align__(16) unsigned char smem[65536];
    const int bid = blockIdx.x;
    const int tid = threadIdx.x;
    const int lane = tid & 63;
    const int wave = tid >> 6;
    const int fr = lane & 15;
    const int rq = (lane >> 4) * 4;

    if (bid < 256) {
        const int x  = bid & 7;                 // XCD
        const int q  = bid >> 3;                // 0..31
        const int kh = x >> 2;                  // K-half
        const int rt = ((x & 3) << 3) + (q & 7);// row-tile 0..31
        const int ct = q >> 3;                  // col-tile 0..3
        const int row0 = rt * 128;
        const int col0 = ct * 128;
        f32x4 acc[4][4] = {};
        gemm8_db<4>(A8, hwT8, kh * 2048, 2048, row0, col0,
                    smem, smem + 32768, acc);
        float* Pz = kh ? P1 : P0;
        const int wr = (wave >> 1) * 64;
        const int wc = (wave & 1) * 64;
        #pragma unroll
        for (int i = 0; i < 4; i++)
            #pragma unroll
            for (int j = 0; j < 4; j++) {
                int c = col0 + wc + j * 16 + fr;
                int rbase = row0 + wr + i * 16 + rq;
                #pragma unroll
                for (int r = 0; r < 4; r++)
                    Pz[(size_t)(rbase + r) * 512 + c] = acc[i][j][r];
            }
    } else {
        // ---- gates: z = [h|x] @ Wz + b -> LSTM elementwise ----
        const int b2 = bid - 256;
        f32x4 acc[4][4] = {};
        const int row0 = (b2 >> 3) * 128;
        const int col0 = (b2 & 7) * 128;
        gemm_core_db<4>(HCb, KG, WzTb, KG, KG, row0, col0,
                        (unsigned short*)smem, (unsigned short*)(smem + 32768), acc);
        const int wr = (wave >> 1) * 64, wc = (wave & 1) * 64;
        const int g = lane & 3;
        #pragma unroll
        for (int i = 0; i < 4; i++)
            #pragma unroll
            for (int j = 0; j < 4; j++) {
                int c = col0 + wc + j * 16 + fr;
                int rbase = row0 + wr + i * 16 + rq;
                float bias = biasg[c];
                int h = c >> 2;
                #pragma unroll
                for (int r = 0; r < 4; r++) {
                    float v = acc[i][j][r] + bias;
                    float z_i = __shfl(v, (lane & ~3) | 0, 64);
                    float z_f = __shfl(v, (lane & ~3) | 1, 64);
                    float z_g = __shfl(v, (lane & ~3) | 2, 64);
                    float z_o = __shfl(v, (lane & ~3) | 3, 64);
                    if (g < 2) {
                        int n = rbase + r;
                        float cp = Cstate[n * HH + h];
                        float ccur = sigmoidf_(z_f) * cp + sigmoidf_(z_i) * tanhf_(z_g);
                        if (g == 0) {
                            float hcur = sigmoidf_(z_o) * tanhf_(ccur);
                            LHS2[(size_t)n * 512 + h] = f2bf(hcur);
                        } else {
                            LHS2[(size_t)n * 512 + 256 + h] = f2bf(ccur);
                        }
                    }
                }
            }
    }
}

// k_uf (fused): per block: 32 rows x one U-half (256 cols).
//  stage1: U = sigmoid([cur | tanh(graph)] @ WU + b), K=512.
//    K-chunks 0-3: cur bf16 from LHS2 (async16).
//    K-chunks 4-7: graph = tanh((P0+P1)*AINV2 + bg) computed during staging.
//  epilogue: U -> LDS (swizzled bf16), HCb/Cstate, out_pred (half 0)
//  stage2: HW = U @ Wg^T (K=256, block-local) -> x64 -> fp8 transposed hwT8
__global__ __launch_bounds__(256) void k_uf(
    const unsigned short* __restrict__ LHS2,  // [4096][512]
    const unsigned short* __restrict__ WU,    // [512][512]
    const unsigned short* __restrict__ WgT,   // [512][256]
    const float* __restrict__ b_h, const float* __restrict__ b_c,
    const float* __restrict__ bgh, const float* __restrict__ bgc,
    const float* __restrict__ W_out, const float* __restrict__ b_out,
    float* __restrict__ Cstate,
    unsigned short* __restrict__ HCb,
    unsigned char* __restrict__ hwT8,         // [512][4096]
    float* __restrict__ d_out,
    const float* __restrict__ inputs,
    const float* __restrict__ P0, const float* __restrict__ P1, int t)
{
    // LDS: stage1 As 2x(32x64) @0 (8KB), Bs 2x(256x64) @8K (64KB)
    //      stage2 alias: Us (32x256) @0 (16KB), B2s (256x64) @16K (32KB)
    //      outred @72K (1KB)
    __shared__ __align__(16) unsigned char smem[74752];
    unsigned short* As  = (unsigned short*)smem;
    unsigned short* Bs  = (unsigned short*)(smem + 8192);
    unsigned short* Us  = (unsigned short*)smem;
    unsigned short* B2s = (unsigned short*)(smem + 16384);
    float* outred = (float*)(smem + 73728);

    const int bid  = blockIdx.x;
    const int tid  = threadIdx.x;
    const int lane = tid & 63;
    const int wave = tid >> 6;
    const int fr   = lane & 15;
    const int fq   = lane >> 4;
    const int rq   = fq * 4;
    const int srow = lane >> 3;
    const int sblk = lane & 7;

    const int half = bid & 1;
    const int row0 = (bid >> 1) * 32;
    const int wc   = wave * 64;
    const int off0 = ((fq ^ (fr & 7)) * 8);
    const int ABUF = 2048, BBUF = 16384;

    const unsigned short* Ag = LHS2 + half*256
        + (size_t)(row0 + wave*8 + srow) * 512 + ((sblk ^ srow) * 8);
    const unsigned short* Bg = WU
        + (size_t)(half*256 + wave*64 + srow) * 512 + ((sblk ^ srow) * 8);
    const float* Pg0 = P0 + (size_t)row0 * 512 + half*256;
    const float* Pg1 = P1 + (size_t)row0 * 512 + half*256;
    const float* bgp = half ? bgc : bgh;
    const int arow = tid >> 3;
    const int kb8  = tid & 7;

    // prologue: stage chunk 0 (cur half)
    async16(Ag, As + wave*512);
    #pragma unroll
    for (int q = 0; q < 8; q++)
        async16(Bg + (size_t)q*8*512, Bs + wave*4096 + q*512);
    asm volatile("s_waitcnt vmcnt(0)" ::: "memory");
    __syncthreads();

    f32x4 acc[2][4] = {};
    int sel = 0;
    for (int it = 0; it < 8; ++it) {
        const int nit = it + 1;
        if (nit < 8) {
            #pragma unroll
            for (int q = 0; q < 8; q++)
                async16(Bg + nit*64 + (size_t)q*8*512,
                        Bs + (sel^1)*BBUF + wave*4096 + q*512);
            if (nit < 4)
                async16(Ag + nit*64, As + (sel^1)*ABUF + wave*512);
        }
        // MFMA on current chunk
        {
            const unsigned short* Ab = As + sel*ABUF;
            const unsigned short* Bb = Bs + sel*BBUF;
            #pragma unroll
            for (int kh2 = 0; kh2 < 2; kh2++) {
                const int off = off0 ^ (kh2 * 32);
                short8 a[2], b[4];
                #pragma unroll
                for (int i = 0; i < 2; i++)
                    a[i] = *(const short8*)(Ab + (i*16 + fr) * 64 + off);
                #pragma unroll
                for (int j = 0; j < 4; j++)
                    b[j] = *(const short8*)(Bb + (wc + j*16 + fr) * 64 + off);
                #pragma unroll
                for (int i = 0; i < 2; i++)
                    #pragma unroll
                    for (int j = 0; j < 4; j++)
                        acc[i][j] = __builtin_amdgcn_mfma_f32_16x16x32_bf16(
                            a[i], b[j], acc[i][j], 0, 0, 0);
            }
        }
        if (nit >= 4 && nit < 8) {
            // graph-chunk staging: tanh((P0+P1)*AINV2 + bg) -> bf16 swizzled
            const int gc0 = (nit - 4) * 64 + kb8 * 8;
            const float* pa = Pg0 + (size_t)arow * 512 + gc0;
            const float* pb = Pg1 + (size_t)arow * 512 + gc0;
            float4 a0 = *(const float4*)pa;
            float4 a1 = *(const float4*)(pa + 4);
            float4 c0 = *(const float4*)pb;
            float4 c1 = *(const float4*)(pb + 4);
            const float* bq = bgp + gc0;
            short8 v;
            v[0] = (short)f2bf(tanhf_((a0.x + c0.x) * AINV2 + bq[0]));
            v[1] = (short)f2bf(tanhf_((a0.y + c0.y) * AINV2 + bq[1]));
            v[2] = (short)f2bf(tanhf_((a0.z + c0.z) * AINV2 + bq[2]));
            v[3] = (short)f2bf(tanhf_((a0.w + c0.w) * AINV2 + bq[3]));
            v[4] = (short)f2bf(tanhf_((a1.x + c1.x) * AINV2 + bq[4]));
            v[5] = (short)f2bf(tanhf_((a1.y + c1.y) * AINV2 + bq[5]));
            v[6] = (short)f2bf(tanhf_((a1.z + c1.z) * AINV2 + bq[6]));
            v[7] = (short)f2bf(tanhf_((a1.w + c1.w) * AINV2 + bq[7]));
            *(short8*)(As + (sel^1)*ABUF + arow*64 + ((kb8 ^ (arow & 7)) * 8)) = v;
        }
        asm volatile("s_waitcnt vmcnt(0)" ::: "memory");
        __syncthreads();
        sel ^= 1;
    }

    // ---- stage-1 epilogue: sigmoid, write Us(swizzled)/HCb/Cstate, out partials
    const float* bias = half ? b_c : b_h;
    float pr0[8], pr1[8];
    #pragma unroll
    for (int m = 0; m < 8; m++) { pr0[m] = 0.f; pr1[m] = 0.f; }
    #pragma unroll
    for (int i = 0; i < 2; i++)
        #pragma unroll
        for (int j = 0; j < 4; j++) {
            const int cl = wc + j*16 + fr;                // 0..255 within half
            const float bv = bias[cl];
            const int blk = j*2 + (fr >> 3);
            float w0 = 0.f, w1 = 0.f;
            if (half == 0) { w0 = W_out[cl*2 + 0]; w1 = W_out[cl*2 + 1]; }
            #pragma unroll
            for (int r = 0; r < 4; r++) {
                const int rl = i*16 + rq + r;             // 0..31
                const int n = row0 + rl;
                float v = sigmoidf_(acc[i][j][r] + bv);
                unsigned short vb = f2bf(v);
                Us[rl*256 + wave*64 + ((blk ^ (rl & 7)) * 8) + (fr & 7)] = vb;
                if (half == 0) {
                    HCb[(size_t)n * KG + cl] = vb;
                    pr0[i*4 + r] += v * w0;
                    pr1[i*4 + r] += v * w1;
                } else {
                    Cstate[(size_t)n * HH + cl] = v;
                }
            }
        }
    if (half == 0) {
        #pragma unroll
        for (int m = 0; m < 8; m++) {
            #pragma unroll
            for (int s = 1; s < 16; s <<= 1) {
                pr0[m] += __shfl_xor(pr0[m], s, 64);
                pr1[m] += __shfl_xor(pr1[m], s, 64);
            }
        }
        if (fr == 0) {
            #pragma unroll
            for (int i = 0; i < 2; i++)
                #pragma unroll
                for (int r = 0; r < 4; r++) {
                    int rl = i*16 + rq + r;
                    outred[(wave*32 + rl)*2 + 0] = pr0[i*4 + r];
                    outred[(wave*32 + rl)*2 + 1] = pr1[i*4 + r];
                }
        }
    }
    __syncthreads();   // Us + outred visible
    if (half == 0 && tid < 64) {
        int rl = tid >> 1, p = tid & 1;
        float s = b_out[p];
        #pragma unroll
        for (int w = 0; w < 4; w++) s += outred[(w*32 + rl)*2 + p];
        d_out[(size_t)(row0 + rl) * TP + t * PP + p] = s;
    }

    // ---- stage 2: HW = U @ Wg^T, K=256 (block-local), 4 chunks
    f32x4 acc2[2][4] = {};
    const unsigned short* Bg2 = WgT
        + (size_t)(half*256 + wave*64 + srow) * 256 + ((sblk ^ srow) * 8);
    for (int kc2 = 0; kc2 < 4; ++kc2) {
        __syncthreads();           // previous chunk's reads done
        #pragma unroll
        for (int q = 0; q < 8; q++)
            async16(Bg2 + (size_t)q*8*256 + kc2*64, B2s + wave*4096 + q*512);
        asm volatile("s_waitcnt vmcnt(0)" ::: "memory");
        __syncthreads();
        #pragma unroll
        for (int kh2 = 0; kh2 < 2; kh2++) {
            const int off = off0 ^ (kh2 * 32);
            short8 a[2], b[4];
            #pragma unroll
            for (int i = 0; i < 2; i++)
                a[i] = *(const short8*)(Us + (i*16 + fr) * 256 + kc2*64 + off);
            #pragma unroll
            for (int j = 0; j < 4; j++)
                b[j] = *(const short8*)(B2s + (wc + j*16 + fr) * 64 + off);
            #pragma unroll
            for (int i = 0; i < 2; i++)
                #pragma unroll
                for (int j = 0; j < 4; j++)
                    acc2[i][j] = __builtin_amdgcn_mfma_f32_16x16x32_bf16(
                        a[i], b[j], acc2[i][j], 0, 0, 0);
        }
    }
    // hwT8[cg][n] fp8 transposed store
    #pragma unroll
    for (int i = 0; i < 2; i++)
        #pragma unroll
        for (int j = 0; j < 4; j++) {
            int cg = half*256 + wc + j*16 + fr;
            int rbase = row0 + i*16 + rq;
            unsigned pk = (unsigned)f2e4m3(acc2[i][j][0] * HWSCALE)
                        | ((unsigned)f2e4m3(acc2[i][j][1] * HWSCALE) << 8)
                        | ((unsigned)f2e4m3(acc2[i][j][2] * HWSCALE) << 16)
                        | ((unsigned)f2e4m3(acc2[i][j][3] * HWSCALE) << 24);
            *(unsigned*)(hwT8 + (size_t)cg * NN + rbase) = pk;
        }

    // x_{t+1} prefetch into HCb
    int gid = bid * 256 + tid;                            // 0..65535
    if (t + 1 < TT) {
        int n = gid >> 4, d = gid & 15;
        HCb[(size_t)n * KG + 256 + d] = f2bf(inputs[(size_t)n * TD + (t + 1) * DD + d]);
    }
}

extern "C" void kernel_launch(void* const* d_in, const int* in_sizes, int n_in,
                              void* d_out_v, int out_size, void* d_ws, size_t ws_size,
                              hipStream_t stream)
{
    const float* inputs = (const float*)d_in[0];
    const float* A      = (const float*)d_in[1];
    const float* kern   = (const float*)d_in[2];
    const float* rk     = (const float*)d_in[3];
    const float* lb     = (const float*)d_in[4];
    const float* Wgh    = (const float*)d_in[5];
    const float* bgh    = (const float*)d_in[6];
    const float* Wgc    = (const float*)d_in[7];
    const float* bgc    = (const float*)d_in[8];
    const float* Whc    = (const float*)d_in[9];
    const float* Whp    = (const float*)d_in[10];
    const float* bh     = (const float*)d_in[11];
    const float* Wcc    = (const float*)d_in[12];
    const float* Wcp    = (const float*)d_in[13];
    const float* bc     = (const float*)d_in[14];
    const float* Wout   = (const float*)d_in[15];
    const float* bout   = (const float*)d_in[16];
    float* d_out = (float*)d_out_v;

    char* ws = (char*)d_ws;
    size_t off = 0;
    auto alloc = [&](size_t bytes) {
        char* p = ws + off;
        off += (bytes + 255) & ~(size_t)255;
        return p;
    };
    unsigned char*  A8    = (unsigned char*) alloc((size_t)NN * NN);           // 16 MB
    unsigned char*  hwT8  = (unsigned char*) alloc((size_t)512 * NN);          // 2 MB
    unsigned short* HCb   = (unsigned short*)alloc((size_t)NN * KG * 2);       // 2.5 MB
    unsigned short* WzTb  = (unsigned short*)alloc((size_t)1024 * KG * 2);
    unsigned short* WgT   = (unsigned short*)alloc((size_t)512 * 256 * 2);
    unsigned short* WU    = (unsigned short*)alloc((size_t)512 * 512 * 2);
    float*          biasg = (float*)         alloc(1024 * 4);
    unsigned short* LHS2  = (unsigned short*)alloc((size_t)NN * 512 * 2);      // 4 MB
    float*          Cst   = (float*)         alloc((size_t)NN * HH * 4);       // 4 MB
    float*          P0    = (float*)         alloc((size_t)NN * 512 * 4);      // 8 MB
    float*          P1    = (float*)         alloc((size_t)NN * 512 * 4);      // 8 MB
    (void)in_sizes; (void)n_in; (void)out_size; (void)ws_size;

    k_prep_a<<<2048, 256, 0, stream>>>(A, A8);
    k_prep_w<<<256, 256, 0, stream>>>(Wgh, Wgc, rk, kern, lb,
                                      Whc, Whp, Wcc, Wcp, WzTb, WgT, WU, biasg);
    k_prep_s<<<512, 256, 0, stream>>>(inputs, HCb, hwT8, Cst);

    for (int t = 0; t < TT; t++) {
        k_a<<<512, 256, 0, stream>>>(A8, hwT8, HCb, WzTb, biasg, Cst,
                                     LHS2, P0, P1);
        k_uf<<<256, 256, 0, stream>>>(LHS2, WU, WgT, bh, bc, bgh, bgc,
                                      Wout, bout, Cst, HCb, hwT8, d_out,
                                      inputs, P0, P1, t);
    }
}

// Round 5
// 20128.268 us; speedup vs baseline: 1.4935x; 1.0561x over previous
//
#include <hip/hip_runtime.h>

using short8 = __attribute__((ext_vector_type(8))) short;
using f32x4  = __attribute__((ext_vector_type(4))) float;

#define NN 4096
#define TT 365
#define DD 16
#define HH 256
#define PP 2
#define TD (TT*DD)      // 5840
#define TP (TT*PP)      // 730
#define KG 320          // gates K: [h(256) | x(16) | pad(48)]
#define ASCALE 4096.0f
#define HWSCALE 64.0f
#define AINV2 (1.0f/(4096.0f*64.0f))   // A8 scale * hwT8 scale

__device__ __forceinline__ unsigned short f2bf(float f) {
    union { float f; unsigned u; } v; v.f = f;
    unsigned r = v.u + 0x7FFFu + ((v.u >> 16) & 1u);   // RNE
    return (unsigned short)(r >> 16);
}
// float -> OCP e4m3fn, RNE, saturating at 448
__device__ __forceinline__ unsigned char f2e4m3(float f) {
    union { float f; unsigned u; } v; v.f = f;
    unsigned s = (v.u >> 24) & 0x80u;
    unsigned au = v.u & 0x7fffffffu;
    if (au >= 0x43E00000u) return (unsigned char)(s | 0x7E);   // >=448 -> 448
    if (au < 0x3C800000u) {                                    // <2^-6: subnormal
        int m = __float2int_rn(__uint_as_float(au) * 512.0f);  // 0..8
        return (unsigned char)(s | (unsigned)m);
    }
    unsigned r = au + 0x7FFFFu + ((au >> 20) & 1u);            // RNE to 3 mantissa bits
    return (unsigned char)(s | ((r >> 20) - 0x3C0u));
}
__device__ __forceinline__ float sigmoidf_(float x) {
    return 1.0f / (1.0f + __expf(-x));
}
__device__ __forceinline__ float tanhf_(float x) {
    float t = __expf(2.0f * x);
    return (t - 1.0f) / (t + 1.0f);
}
__device__ __forceinline__ void async16(const void* g, void* l) {
    __builtin_amdgcn_global_load_lds(
        (const __attribute__((address_space(1))) void*)g,
        (__attribute__((address_space(3))) void*)l, 16, 0, 0);
}

// ---------------------------------------------------------------------------
// bf16 core, double-buffered: 256 thr = 4 waves 2x2. BN=128, BK=64, BM=32*TI.
// C = Amat(row-major,lda) @ Bt^T (Bt[col][k],ldb). 16B-block XOR swizzle.
// C frag: col = lane&15, row = (lane>>4)*4 + reg.
// ---------------------------------------------------------------------------
template<int TI>
__device__ __forceinline__ void gemm_core_db(
    const unsigned short* __restrict__ Amat, int lda,
    const unsigned short* __restrict__ Bt,  int ldb,
    int k_len, int row0, int col0,
    unsigned short* As, unsigned short* Bs,
    f32x4 (&acc)[TI][4])
{
    const int tid  = threadIdx.x;
    const int lane = tid & 63;
    const int wave = tid >> 6;
    const int srow = lane >> 3;
    const int sblk = lane & 7;
    const int ABUF = TI * 32 * 64;     // shorts per A buffer
    const int BBUF = 128 * 64;         // shorts per B buffer

    const unsigned short* Ag = Amat + (size_t)(row0 + wave*8 + srow) * lda
                                    + ((sblk ^ srow) * 8);
    const unsigned short* Bg = Bt   + (size_t)(col0 + wave*8 + srow) * ldb
                                    + ((sblk ^ srow) * 8);

    const int fr = lane & 15;
    const int fq = lane >> 4;
    const int wr = (wave >> 1) * (TI * 16);
    const int wc = (wave & 1) * 64;
    const int off0 = ((fq ^ (fr & 7)) * 8);

    {
        unsigned short* AsW = As + wave * 512;
        unsigned short* BsW = Bs + wave * 512;
        #pragma unroll
        for (int q = 0; q < TI; q++) async16(Ag + (size_t)q * 32 * lda, AsW + q * 2048);
        #pragma unroll
        for (int q = 0; q < 4;  q++) async16(Bg + (size_t)q * 32 * ldb, BsW + q * 2048);
    }
    asm volatile("s_waitcnt vmcnt(0)" ::: "memory");
    __syncthreads();

    const int nk = k_len >> 6;
    int sel = 0;
    for (int it = 0; it < nk; ++it) {
        if (it + 1 < nk) {
            const unsigned short* Agn = Ag + (it + 1) * 64;
            const unsigned short* Bgn = Bg + (it + 1) * 64;
            unsigned short* AsW = As + (sel ^ 1) * ABUF + wave * 512;
            unsigned short* BsW = Bs + (sel ^ 1) * BBUF + wave * 512;
            #pragma unroll
            for (int q = 0; q < TI; q++) async16(Agn + (size_t)q * 32 * lda, AsW + q * 2048);
            #pragma unroll
            for (int q = 0; q < 4;  q++) async16(Bgn + (size_t)q * 32 * ldb, BsW + q * 2048);
        }
        const unsigned short* Ab = As + sel * ABUF;
        const unsigned short* Bb = Bs + sel * BBUF;
        #pragma unroll
        for (int kh = 0; kh < 2; kh++) {
            const int off = off0 ^ (kh * 32);
            short8 a[TI], b[4];
            #pragma unroll
            for (int i = 0; i < TI; i++)
                a[i] = *(const short8*)(Ab + (wr + i*16 + fr) * 64 + off);
            #pragma unroll
            for (int j = 0; j < 4;  j++)
                b[j] = *(const short8*)(Bb + (wc + j*16 + fr) * 64 + off);
            #pragma unroll
            for (int i = 0; i < TI; i++)
                #pragma unroll
                for (int j = 0; j < 4; j++)
                    acc[i][j] = __builtin_amdgcn_mfma_f32_16x16x32_bf16(
                        a[i], b[j], acc[i][j], 0, 0, 0);
        }
        asm volatile("s_waitcnt vmcnt(0)" ::: "memory");
        __syncthreads();
        sel ^= 1;
    }
}

// ---------------------------------------------------------------------------
// fp8 core, double-buffered, BM=32*TI x 128 tile: C = A8 @ B8^T, both
// row-major [*][NN] bytes, BK=128.
// ---------------------------------------------------------------------------
template<int TI>
__device__ __forceinline__ void gemm8_db(
    const unsigned char* __restrict__ Amat,
    const unsigned char* __restrict__ Bmat,
    int kb, int klen, int row0, int col0,
    unsigned char* As, unsigned char* Bs,
    f32x4 (&acc)[TI][4])
{
    const int tid  = threadIdx.x;
    const int lane = tid & 63;
    const int wave = tid >> 6;
    const int srow = lane >> 3;
    const int sblk = lane & 7;
    const int ABUF = TI * 32 * 128;
    const int BBUF = 128 * 128;

    const unsigned char* Ag = Amat + (size_t)(row0 + wave*8 + srow) * NN
                                   + ((sblk ^ srow) * 16) + kb;
    const unsigned char* Bg = Bmat + (size_t)(col0 + wave*8 + srow) * NN
                                   + ((sblk ^ srow) * 16) + kb;

    const int fr = lane & 15;
    const int fq = lane >> 4;
    const int wr = (wave >> 1) * (TI * 16);
    const int wc = (wave & 1) * 64;
    int offk[4];
    #pragma unroll
    for (int kq = 0; kq < 4; kq++)
        offk[kq] = (((kq*2 + (fq >> 1)) ^ (fr & 7)) << 4) + ((fq & 1) << 3);

    {
        unsigned char* AsW = As + wave * 1024;
        unsigned char* BsW = Bs + wave * 1024;
        #pragma unroll
        for (int q = 0; q < TI; q++) async16(Ag + (size_t)q * 32 * NN, AsW + q * 4096);
        #pragma unroll
        for (int q = 0; q < 4;  q++) async16(Bg + (size_t)q * 32 * NN, BsW + q * 4096);
    }
    asm volatile("s_waitcnt vmcnt(0)" ::: "memory");
    __syncthreads();

    const int nk = klen >> 7;
    int sel = 0;
    for (int it = 0; it < nk; ++it) {
        if (it + 1 < nk) {
            const unsigned char* Agn = Ag + (size_t)(it + 1) * 128;
            const unsigned char* Bgn = Bg + (size_t)(it + 1) * 128;
            unsigned char* AsW = As + (sel ^ 1) * ABUF + wave * 1024;
            unsigned char* BsW = Bs + (sel ^ 1) * BBUF + wave * 1024;
            #pragma unroll
            for (int q = 0; q < TI; q++) async16(Agn + (size_t)q * 32 * NN, AsW + q * 4096);
            #pragma unroll
            for (int q = 0; q < 4;  q++) async16(Bgn + (size_t)q * 32 * NN, BsW + q * 4096);
        }
        const unsigned char* Ab = As + sel * ABUF;
        const unsigned char* Bb = Bs + sel * BBUF;
        #pragma unroll
        for (int kq = 0; kq < 4; kq++) {
            long a[TI], b[4];
            #pragma unroll
            for (int i = 0; i < TI; i++) a[i] = *(const long*)(Ab + (wr + i*16 + fr) * 128 + offk[kq]);
            #pragma unroll
            for (int j = 0; j < 4;  j++) b[j] = *(const long*)(Bb + (wc + j*16 + fr) * 128 + offk[kq]);
            #pragma unroll
            for (int i = 0; i < TI; i++)
                #pragma unroll
                for (int j = 0; j < 4; j++)
                    acc[i][j] = __builtin_amdgcn_mfma_f32_16x16x32_fp8_fp8(
                        a[i], b[j], acc[i][j], 0, 0, 0);
        }
        asm volatile("s_waitcnt vmcnt(0)" ::: "memory");
        __syncthreads();
        sel ^= 1;
    }
}

// ---------------- prep (once per launch) ----------------

__global__ __launch_bounds__(256) void k_prep_a(const float* __restrict__ A,
                                                unsigned char* __restrict__ A8) {
    size_t i = (size_t)blockIdx.x * blockDim.x + threadIdx.x;
    size_t stride = (size_t)gridDim.x * blockDim.x;
    size_t total = (size_t)NN * NN / 4;
    for (; i < total; i += stride) {
        float4 v = ((const float4*)A)[i];
        unsigned pk = (unsigned)f2e4m3(v.x * ASCALE)
                    | ((unsigned)f2e4m3(v.y * ASCALE) << 8)
                    | ((unsigned)f2e4m3(v.z * ASCALE) << 16)
                    | ((unsigned)f2e4m3(v.w * ASCALE) << 24);
        ((unsigned*)A8)[i] = pk;
    }
}

__global__ __launch_bounds__(256) void k_prep_w(
    const float* __restrict__ Wgh, const float* __restrict__ Wgc,
    const float* __restrict__ rk,  const float* __restrict__ kern,
    const float* __restrict__ lb,
    const float* __restrict__ Whc, const float* __restrict__ Whp,
    const float* __restrict__ Wcc, const float* __restrict__ Wcp,
    unsigned short* __restrict__ WzTb, unsigned short* __restrict__ WgT,
    unsigned short* __restrict__ WU, float* __restrict__ biasg)
{
    int i = blockIdx.x * blockDim.x + threadIdx.x;
    int stride = gridDim.x * blockDim.x;
    for (int x = i; x < 1024 * KG; x += stride) {
        int col = x / KG, k = x % KG;
        int oc = (col & 3) * 256 + (col >> 2);
        float val = 0.f;
        if (k < 256) val = rk[k * 1024 + oc];
        else if (k < 272) val = kern[(k - 256) * 1024 + oc];
        WzTb[x] = f2bf(val);
    }
    for (int x = i; x < 512 * 256; x += stride) {
        int col = x >> 8, k = x & 255;
        float val = (col < 256) ? Wgh[k * 256 + col] : Wgc[k * 256 + (col - 256)];
        WgT[x] = f2bf(val);
    }
    for (int x = i; x < 512 * 512; x += stride) {
        int col = x >> 9, k = x & 511;
        float val;
        if (col < 256)
            val = (k < 256) ? Whc[k * 256 + col] : Whp[(k - 256) * 256 + col];
        else {
            int c2 = col - 256;
            val = (k < 256) ? Wcc[k * 256 + c2] : Wcp[(k - 256) * 256 + c2];
        }
        WU[x] = f2bf(val);
    }
    for (int x = i; x < 1024; x += stride)
        biasg[x] = lb[(x & 3) * 256 + (x >> 2)];
}

__global__ __launch_bounds__(256) void k_prep_s(const float* __restrict__ inputs,
                                                unsigned short* __restrict__ HCb,
                                                unsigned char* __restrict__ hwT8,
                                                float* __restrict__ Cstate)
{
    int i = blockIdx.x * blockDim.x + threadIdx.x;
    int stride = gridDim.x * blockDim.x;
    for (int x = i; x < NN * KG; x += stride) {
        int n = x / KG, col = x % KG;
        unsigned short v = 0;
        if (col >= 256 && col < 272)
            v = f2bf(inputs[(size_t)n * TD + (col - 256)]);
        HCb[x] = v;
    }
    for (int x = i; x < 512 * NN / 4; x += stride) ((unsigned*)hwT8)[x] = 0;
    for (int x = i; x < NN * HH; x += stride) Cstate[x] = 0.f;
}

// ---------------- per-step kernels ----------------

// kA: 512 blocks, 2/CU.
//  bid<256: graph states, 64x128 tiles, K=4096 complete:
//    G = tanh(A8 @ hwT8^T * AINV2 + bg) -> LHS3 graph cols (bf16).
//    XCD-aware: xcd = bid&7 owns 8 row-tiles x all 4 col-tiles
//    (A-slice 2MB + hwT8 2MB ~ L2-resident).
//  bid>=256: gates GEMM + LSTM elementwise -> LHS3 cur cols.
// LHS3: [h_cur(0-255) | h_graph(256-511) | c_cur(512-767) | c_graph(768-1023)]
__global__ __launch_bounds__(256, 2) void k_a(
    const unsigned char* __restrict__ A8,     // [4096][4096] (x4096 scale)
    const unsigned char* __restrict__ hwT8,   // [512][4096]: HWh 0-255, HWc 256-511 (x64)
    const float* __restrict__ bgh, const float* __restrict__ bgc,
    const unsigned short* __restrict__ HCb,   // [4096][KG]
    const unsigned short* __restrict__ WzTb,  // [1024][KG]
    const float* __restrict__ biasg,
    const float* __restrict__ Cstate,
    unsigned short* __restrict__ LHS3)        // [4096][1024]
{
    __shared__ __align__(16) unsigned char smem[65536];
    const int bid = blockIdx.x;
    const int tid = threadIdx.x;
    const int lane = tid & 63;
    const int wave = tid >> 6;
    const int fr = lane & 15;
    const int rq = (lane >> 4) * 4;

    if (bid < 256) {
        // XCD remap: xcd = bid&7 -> row-tiles [xcd*8, xcd*8+8), col-tiles 0..3
        const int x  = bid & 7;
        const int q  = bid >> 3;                // 0..31
        const int row0 = (x * 8 + (q & 7)) * 64;
        const int col0 = (q >> 3) * 128;
        f32x4 acc[2][4] = {};
        gemm8_db<2>(A8, hwT8, 0, NN, row0, col0, smem, smem + 16384, acc);
        const int wr = (wave >> 1) * 32;
        const int wc = (wave & 1) * 64;
        #pragma unroll
        for (int i = 0; i < 2; i++)
            #pragma unroll
            for (int j = 0; j < 4; j++) {
                int c = col0 + wc + j * 16 + fr;          // HW col 0..511
                float bias = (c < 256) ? bgh[c] : bgc[c - 256];
                int dst = (c < 256) ? (c + 256) : (c + 512);
                int rbase = row0 + wr + i * 16 + rq;
                #pragma unroll
                for (int r = 0; r < 4; r++)
                    LHS3[(size_t)(rbase + r) * 1024 + dst] =
                        f2bf(tanhf_(acc[i][j][r] * AINV2 + bias));
            }
    } else {
        // ---- gates: z = [h|x] @ Wz + b -> LSTM elementwise ----
        const int b2 = bid - 256;
        f32x4 acc[4][4] = {};
        const int row0 = (b2 >> 3) * 128;
        const int col0 = (b2 & 7) * 128;
        gemm_core_db<4>(HCb, KG, WzTb, KG, KG, row0, col0,
                        (unsigned short*)smem, (unsigned short*)(smem + 32768), acc);
        const int wr = (wave >> 1) * 64, wc = (wave & 1) * 64;
        const int g = lane & 3;
        #pragma unroll
        for (int i = 0; i < 4; i++)
            #pragma unroll
            for (int j = 0; j < 4; j++) {
                int c = col0 + wc + j * 16 + fr;
                int rbase = row0 + wr + i * 16 + rq;
                float bias = biasg[c];
                int h = c >> 2;
                #pragma unroll
                for (int r = 0; r < 4; r++) {
                    float v = acc[i][j][r] + bias;
                    float z_i = __shfl(v, (lane & ~3) | 0, 64);
                    float z_f = __shfl(v, (lane & ~3) | 1, 64);
                    float z_g = __shfl(v, (lane & ~3) | 2, 64);
                    float z_o = __shfl(v, (lane & ~3) | 3, 64);
                    if (g < 2) {
                        int n = rbase + r;
                        float cp = Cstate[n * HH + h];
                        float ccur = sigmoidf_(z_f) * cp + sigmoidf_(z_i) * tanhf_(z_g);
                        if (g == 0) {
                            float hcur = sigmoidf_(z_o) * tanhf_(ccur);
                            LHS3[(size_t)n * 1024 + h] = f2bf(hcur);
                        } else {
                            LHS3[(size_t)n * 1024 + 512 + h] = f2bf(ccur);
                        }
                    }
                }
            }
    }
}

// k_uf (fused): 512 blocks (2/CU), per block: 16 rows x one U-half (256 cols).
//  stage1: U = sigmoid(LHS3[:,half*512:+512] @ WU[:,half*256:+256] + b), K=512,
//          fully uniform async16 staging (8 chunks).
//  epilogue: U -> LDS (swizzled bf16), HCb/Cstate, out_pred (half 0)
//  stage2: HW = U @ Wg^T (K=256, block-local) -> x64 -> fp8 transposed hwT8
//  wave layout 1x4: wave w owns cols w*64..w*64+63.
__global__ __launch_bounds__(256) void k_uf(
    const unsigned short* __restrict__ LHS3,  // [4096][1024]
    const unsigned short* __restrict__ WU,    // [512][512]
    const unsigned short* __restrict__ WgT,   // [512][256]
    const float* __restrict__ b_h, const float* __restrict__ b_c,
    const float* __restrict__ W_out, const float* __restrict__ b_out,
    float* __restrict__ Cstate,
    unsigned short* __restrict__ HCb,
    unsigned char* __restrict__ hwT8,         // [512][4096]
    float* __restrict__ d_out,
    const float* __restrict__ inputs, int t)
{
    // LDS map:
    //  stage1: As @0 (2 x 16x64 shorts = 4KB), Bs @8192 (2 x 256x64 = 64KB)
    //  stage2 alias: Us @0 (16x256 shorts = 8KB), B2s @16384 (256x64 = 32KB)
    //  outred @73728 (512B)
    __shared__ __align__(16) unsigned char smem[74752];
    unsigned short* As  = (unsigned short*)smem;
    unsigned short* Bs  = (unsigned short*)(smem + 8192);
    unsigned short* Us  = (unsigned short*)smem;
    unsigned short* B2s = (unsigned short*)(smem + 16384);
    float* outred = (float*)(smem + 73728);

    const int bid  = blockIdx.x;
    const int tid  = threadIdx.x;
    const int lane = tid & 63;
    const int wave = tid >> 6;
    const int fr   = lane & 15;
    const int fq   = lane >> 4;
    const int rq   = fq * 4;
    const int srow = lane >> 3;
    const int sblk = lane & 7;

    const int half = bid & 1;
    const int row0 = (bid >> 1) * 16;
    const int wc   = wave * 64;
    const int off0 = ((fq ^ (fr & 7)) * 8);
    const int ABUF = 1024, BBUF = 16384;      // shorts per buffer

    const unsigned short* Ag = LHS3 + half*512
        + (size_t)(row0 + wave*8 + srow) * 1024 + ((sblk ^ srow) * 8);
    const unsigned short* Bg = WU
        + (size_t)(half*256 + wave*64 + srow) * 512 + ((sblk ^ srow) * 8);

    // prologue: stage chunk 0
    if (wave < 2) async16(Ag, As + wave*512);
    #pragma unroll
    for (int q = 0; q < 8; q++)
        async16(Bg + (size_t)q*8*512, Bs + wave*4096 + q*512);
    asm volatile("s_waitcnt vmcnt(0)" ::: "memory");
    __syncthreads();

    f32x4 acc[4] = {};
    int sel = 0;
    for (int it = 0; it < 8; ++it) {
        const int nit = it + 1;
        if (nit < 8) {
            if (wave < 2) async16(Ag + nit*64, As + (sel^1)*ABUF + wave*512);
            #pragma unroll
            for (int q = 0; q < 8; q++)
                async16(Bg + nit*64 + (size_t)q*8*512,
                        Bs + (sel^1)*BBUF + wave*4096 + q*512);
        }
        const unsigned short* Ab = As + sel*ABUF;
        const unsigned short* Bb = Bs + sel*BBUF;
        #pragma unroll
        for (int kh2 = 0; kh2 < 2; kh2++) {
            const int off = off0 ^ (kh2 * 32);
            short8 a = *(const short8*)(Ab + fr * 64 + off);
            short8 b[4];
            #pragma unroll
            for (int j = 0; j < 4; j++)
                b[j] = *(const short8*)(Bb + (wc + j*16 + fr) * 64 + off);
            #pragma unroll
            for (int j = 0; j < 4; j++)
                acc[j] = __builtin_amdgcn_mfma_f32_16x16x32_bf16(
                    a, b[j], acc[j], 0, 0, 0);
        }
        asm volatile("s_waitcnt vmcnt(0)" ::: "memory");
        __syncthreads();
        sel ^= 1;
    }

    // ---- stage-1 epilogue: sigmoid, write Us(swizzled)/HCb/Cstate, out partials
    const float* bias = half ? b_c : b_h;
    float pr0[4], pr1[4];
    #pragma unroll
    for (int m = 0; m < 4; m++) { pr0[m] = 0.f; pr1[m] = 0.f; }
    #pragma unroll
    for (int j = 0; j < 4; j++) {
        const int cl = wc + j*16 + fr;                // 0..255 within half
        const float bv = bias[cl];
        const int blk = j*2 + (fr >> 3);
        float w0 = 0.f, w1 = 0.f;
        if (half == 0) { w0 = W_out[cl*2 + 0]; w1 = W_out[cl*2 + 1]; }
        #pragma unroll
        for (int r = 0; r < 4; r++) {
            const int rl = rq + r;                    // 0..15
            const int n = row0 + rl;
            float v = sigmoidf_(acc[j][r] + bv);
            unsigned short vb = f2bf(v);
            Us[rl*256 + wave*64 + ((blk ^ (rl & 7)) * 8) + (fr & 7)] = vb;
            if (half == 0) {
                HCb[(size_t)n * KG + cl] = vb;
                pr0[r] += v * w0;
                pr1[r] += v * w1;
            } else {
                Cstate[(size_t)n * HH + cl] = v;
            }
        }
    }
    if (half == 0) {
        #pragma unroll
        for (int m = 0; m < 4; m++) {
            #pragma unroll
            for (int s = 1; s < 16; s <<= 1) {
                pr0[m] += __shfl_xor(pr0[m], s, 64);
                pr1[m] += __shfl_xor(pr1[m], s, 64);
            }
        }
        if (fr == 0) {
            #pragma unroll
            for (int r = 0; r < 4; r++) {
                int rl = rq + r;
                outred[(wave*16 + rl)*2 + 0] = pr0[r];
                outred[(wave*16 + rl)*2 + 1] = pr1[r];
            }
        }
    }
    __syncthreads();   // Us + outred visible
    if (half == 0 && tid < 32) {
        int rl = tid >> 1, p = tid & 1;
        float s = b_out[p];
        #pragma unroll
        for (int w = 0; w < 4; w++) s += outred[(w*16 + rl)*2 + p];
        d_out[(size_t)(row0 + rl) * TP + t * PP + p] = s;
    }

    // ---- stage 2: HW = U @ Wg^T, K=256 (block-local), 4 chunks
    f32x4 acc2[4] = {};
    const unsigned short* Bg2 = WgT
        + (size_t)(half*256 + wave*64 + srow) * 256 + ((sblk ^ srow) * 8);
    for (int kc2 = 0; kc2 < 4; ++kc2) {
        __syncthreads();           // previous chunk's reads done
        #pragma unroll
        for (int q = 0; q < 8; q++)
            async16(Bg2 + (size_t)q*8*256 + kc2*64, B2s + wave*4096 + q*512);
        asm volatile("s_waitcnt vmcnt(0)" ::: "memory");
        __syncthreads();
        #pragma unroll
        for (int kh2 = 0; kh2 < 2; kh2++) {
            const int off = off0 ^ (kh2 * 32);
            short8 a = *(const short8*)(Us + fr * 256 + kc2*64 + off);
            short8 b[4];
            #pragma unroll
            for (int j = 0; j < 4; j++)
                b[j] = *(const short8*)(B2s + (wc + j*16 + fr) * 64 + off);
            #pragma unroll
            for (int j = 0; j < 4; j++)
                acc2[j] = __builtin_amdgcn_mfma_f32_16x16x32_bf16(
                    a, b[j], acc2[j], 0, 0, 0);
        }
    }
    // hwT8[cg][n] fp8 transposed store
    #pragma unroll
    for (int j = 0; j < 4; j++) {
        int cg = half*256 + wc + j*16 + fr;
        int rbase = row0 + rq;
        unsigned pk = (unsigned)f2e4m3(acc2[j][0] * HWSCALE)
                    | ((unsigned)f2e4m3(acc2[j][1] * HWSCALE) << 8)
                    | ((unsigned)f2e4m3(acc2[j][2] * HWSCALE) << 16)
                    | ((unsigned)f2e4m3(acc2[j][3] * HWSCALE) << 24);
        *(unsigned*)(hwT8 + (size_t)cg * NN + rbase) = pk;
    }

    // x_{t+1} prefetch into HCb (half==0 blocks: 256 x 256 threads = 65536)
    if (half == 0 && t + 1 < TT) {
        int gid = (bid >> 1) * 256 + tid;
        int n = gid >> 4, d = gid & 15;
        HCb[(size_t)n * KG + 256 + d] = f2bf(inputs[(size_t)n * TD + (t + 1) * DD + d]);
    }
}

extern "C" void kernel_launch(void* const* d_in, const int* in_sizes, int n_in,
                              void* d_out_v, int out_size, void* d_ws, size_t ws_size,
                              hipStream_t stream)
{
    const float* inputs = (const float*)d_in[0];
    const float* A      = (const float*)d_in[1];
    const float* kern   = (const float*)d_in[2];
    const float* rk     = (const float*)d_in[3];
    const float* lb     = (const float*)d_in[4];
    const float* Wgh    = (const float*)d_in[5];
    const float* bgh    = (const float*)d_in[6];
    const float* Wgc    = (const float*)d_in[7];
    const float* bgc    = (const float*)d_in[8];
    const float* Whc    = (const float*)d_in[9];
    const float* Whp    = (const float*)d_in[10];
    const float* bh     = (const float*)d_in[11];
    const float* Wcc    = (const float*)d_in[12];
    const float* Wcp    = (const float*)d_in[13];
    const float* bc     = (const float*)d_in[14];
    const float* Wout   = (const float*)d_in[15];
    const float* bout   = (const float*)d_in[16];
    float* d_out = (float*)d_out_v;

    char* ws = (char*)d_ws;
    size_t off = 0;
    auto alloc = [&](size_t bytes) {
        char* p = ws + off;
        off += (bytes + 255) & ~(size_t)255;
        return p;
    };
    unsigned char*  A8    = (unsigned char*) alloc((size_t)NN * NN);           // 16 MB
    unsigned char*  hwT8  = (unsigned char*) alloc((size_t)512 * NN);          // 2 MB
    unsigned short* HCb   = (unsigned short*)alloc((size_t)NN * KG * 2);       // 2.5 MB
    unsigned short* WzTb  = (unsigned short*)alloc((size_t)1024 * KG * 2);
    unsigned short* WgT   = (unsigned short*)alloc((size_t)512 * 256 * 2);
    unsigned short* WU    = (unsigned short*)alloc((size_t)512 * 512 * 2);
    float*          biasg = (float*)         alloc(1024 * 4);
    unsigned short* LHS3  = (unsigned short*)alloc((size_t)NN * 1024 * 2);     // 8 MB
    float*          Cst   = (float*)         alloc((size_t)NN * HH * 4);       // 4 MB
    (void)in_sizes; (void)n_in; (void)out_size; (void)ws_size;

    k_prep_a<<<2048, 256, 0, stream>>>(A, A8);
    k_prep_w<<<256, 256, 0, stream>>>(Wgh, Wgc, rk, kern, lb,
                                      Whc, Whp, Wcc, Wcp, WzTb, WgT, WU, biasg);
    k_prep_s<<<512, 256, 0, stream>>>(inputs, HCb, hwT8, Cst);

    for (int t = 0; t < TT; t++) {
        k_a<<<512, 256, 0, stream>>>(A8, hwT8, bgh, bgc,
                                     HCb, WzTb, biasg, Cst, LHS3);
        k_uf<<<512, 256, 0, stream>>>(LHS3, WU, WgT, bh, bc, Wout, bout,
                                      Cst, HCb, hwT8, d_out, inputs, t);
    }
}